// Round 1
// baseline (2528.368 us; speedup 1.0000x reference)
//
#include <hip/hip_runtime.h>
#include <hip/hip_bf16.h>
#include <math.h>

// Problem constants
#define HIDDEN 4096
#define NH 32
#define NKV 8
#define HD 128
#define S_LEN 2048
#define BATCH 2

typedef __attribute__((ext_vector_type(8))) __bf16 bf16x8;
typedef __attribute__((ext_vector_type(4))) float f32x4;

__device__ __forceinline__ f32x4 mfma16(bf16x8 a, bf16x8 b, f32x4 c) {
  return __builtin_amdgcn_mfma_f32_16x16x32_bf16(a, b, c, 0, 0, 0);
}

// ---------------------------------------------------------------------------
// GEMM: C[M,N] = A[M,K] * B[K,N]; A is fp32 or bf16, B fp32 (converted to bf16
// in staging), C is bf16 or fp32. Tile 64x64, BK=32, 4 waves (2x2), each wave
// 32x32 via 2x2 fragments of 16x16x32 MFMA.
// MFMA layouts (gfx950, m89-verified):
//   A-frag: lane l holds A[l&15][(l>>4)*8 + j]      (contiguous k -> b128 read)
//   B-frag: lane l holds B[(l>>4)*8 + j][l&15]      (stored B^T in LDS)
//   D:      lane l reg j -> row=(l>>4)*4+j, col=l&15
// ---------------------------------------------------------------------------
template<typename AT, typename CT>
__global__ __launch_bounds__(256) void gemm_kernel(const AT* __restrict__ A,
                                                   const float* __restrict__ B,
                                                   CT* __restrict__ C,
                                                   int M, int N, int K) {
  __shared__ __bf16 As[64][40];   // [m][k], padded
  __shared__ __bf16 Bs[64][40];   // [n][k] (B transposed), padded

  int tid = threadIdx.x;
  int m0 = blockIdx.y * 64, n0 = blockIdx.x * 64;
  int l = tid & 63, w = tid >> 6;
  int wm = (w >> 1) * 32, wn = (w & 1) * 32;
  int lrow = l & 15, lk = (l >> 4) * 8;

  f32x4 acc[2][2];
#pragma unroll
  for (int i = 0; i < 2; i++)
#pragma unroll
    for (int j = 0; j < 2; j++) {
      acc[i][j][0] = 0.f; acc[i][j][1] = 0.f; acc[i][j][2] = 0.f; acc[i][j][3] = 0.f;
    }

  int arow = tid >> 2, akb = (tid & 3) * 8;    // A stage: 64 rows x 32 k
  int bcol = tid & 63, bkb = (tid >> 6) * 8;   // B stage: 64 cols x 32 k

  for (int k0 = 0; k0 < K; k0 += 32) {
    // stage A tile
    {
      bf16x8 t;
      const AT* ap = A + (size_t)(m0 + arow) * K + (k0 + akb);
      if constexpr (sizeof(AT) == 4) {
        float4 v0 = *reinterpret_cast<const float4*>(ap);
        float4 v1 = *reinterpret_cast<const float4*>(ap + 4);
        t[0] = (__bf16)v0.x; t[1] = (__bf16)v0.y; t[2] = (__bf16)v0.z; t[3] = (__bf16)v0.w;
        t[4] = (__bf16)v1.x; t[5] = (__bf16)v1.y; t[6] = (__bf16)v1.z; t[7] = (__bf16)v1.w;
      } else {
        t = *reinterpret_cast<const bf16x8*>(ap);
      }
      *reinterpret_cast<bf16x8*>(&As[arow][akb]) = t;
    }
    // stage B tile (transposed into LDS)
    {
      bf16x8 t;
      const float* bp = B + (size_t)(k0 + bkb) * N + (n0 + bcol);
#pragma unroll
      for (int i = 0; i < 8; i++) t[i] = (__bf16)bp[(size_t)i * N];
      *reinterpret_cast<bf16x8*>(&Bs[bcol][bkb]) = t;
    }
    __syncthreads();

    bf16x8 af0 = *reinterpret_cast<bf16x8*>(&As[wm + lrow][lk]);
    bf16x8 af1 = *reinterpret_cast<bf16x8*>(&As[wm + 16 + lrow][lk]);
    bf16x8 bf0 = *reinterpret_cast<bf16x8*>(&Bs[wn + lrow][lk]);
    bf16x8 bf1 = *reinterpret_cast<bf16x8*>(&Bs[wn + 16 + lrow][lk]);

    acc[0][0] = mfma16(af0, bf0, acc[0][0]);
    acc[0][1] = mfma16(af0, bf1, acc[0][1]);
    acc[1][0] = mfma16(af1, bf0, acc[1][0]);
    acc[1][1] = mfma16(af1, bf1, acc[1][1]);

    __syncthreads();
  }

#pragma unroll
  for (int mi = 0; mi < 2; mi++)
#pragma unroll
    for (int ni = 0; ni < 2; ni++)
#pragma unroll
      for (int jj = 0; jj < 4; jj++) {
        int row = m0 + wm + mi * 16 + (l >> 4) * 4 + jj;
        int col = n0 + wn + ni * 16 + lrow;
        C[(size_t)row * N + col] = (CT)acc[mi][ni][jj];
      }
}

// ---------------------------------------------------------------------------
// RoPE, in-place on bf16 q/k buffers. grid = (NH+NKV, B*S), block = 64.
// rotate_half convention: out[i] = x[i]*cos - x[i+64]*sin ; out[i+64] =
// x[i+64]*cos + x[i]*sin, cos/sin at angle pos * theta^(-i/64).
// ---------------------------------------------------------------------------
__global__ __launch_bounds__(64) void rope_kernel(__bf16* __restrict__ qb,
                                                  __bf16* __restrict__ kb,
                                                  const int* __restrict__ pos) {
  int pair = threadIdx.x;   // 0..63
  int head = blockIdx.x;    // 0..39 (32 q heads then 8 k heads)
  int row = blockIdx.y;     // 0..B*S-1
  int p = pos[row];
  float inv = powf(10000.0f, -(float)pair * (1.0f / 64.0f));
  float ang = (float)p * inv;
  float c = cosf(ang), s = sinf(ang);
  __bf16* base;
  if (head < NH) base = qb + (size_t)row * (NH * HD) + head * HD;
  else           base = kb + (size_t)row * (NKV * HD) + (head - NH) * HD;
  float x1 = (float)base[pair];
  float x2 = (float)base[pair + 64];
  base[pair]      = (__bf16)(x1 * c - x2 * s);
  base[pair + 64] = (__bf16)(x2 * c + x1 * s);
}

// ---------------------------------------------------------------------------
// Flash attention, causal, GQA (4 q-heads per kv head).
// 1 wave per (b, h, 16-row q tile); kv tiles of 32.
// QK^T: Q as A-frag (direct global b128), K as B-frag (direct global b128).
// Online softmax per row via 16-lane shfl_xor reductions.
// PV: P staged in LDS [16][32->40], V staged transposed [128][40].
// ---------------------------------------------------------------------------
__global__ __launch_bounds__(64) void attn_kernel(const __bf16* __restrict__ q,
                                                  const __bf16* __restrict__ k,
                                                  const __bf16* __restrict__ v,
                                                  __bf16* __restrict__ out) {
  __shared__ __bf16 Ps[16][40];
  __shared__ __bf16 Vst[128][40];

  int l = threadIdx.x;
  int qt = blockIdx.x, h = blockIdx.y, b = blockIdx.z;
  int kvh = h >> 2;
  int q0 = qt * 16;
  int lrow = l & 15, lg = l >> 4, lk = lg * 8;

  bf16x8 qf[4];
  {
    const __bf16* qp = q + (size_t)(b * S_LEN + q0 + lrow) * (NH * HD) + h * HD + lk;
#pragma unroll
    for (int kk = 0; kk < 4; kk++) qf[kk] = *reinterpret_cast<const bf16x8*>(qp + kk * 32);
  }

  f32x4 ov[8];
#pragma unroll
  for (int n = 0; n < 8; n++) { ov[n][0] = 0.f; ov[n][1] = 0.f; ov[n][2] = 0.f; ov[n][3] = 0.f; }
  float m[4]    = {-1e30f, -1e30f, -1e30f, -1e30f};
  float ssum[4] = {0.f, 0.f, 0.f, 0.f};
  const float scale = 0.08838834764831845f;  // 1/sqrt(128)
  int kv_end = q0 + 16;

  for (int kv0 = 0; kv0 < kv_end; kv0 += 32) {
    // ---- scores: two 16x16 col-tiles, K over d in 4 steps of 32
    f32x4 sc[2];
#pragma unroll
    for (int c = 0; c < 2; c++) { sc[c][0] = 0.f; sc[c][1] = 0.f; sc[c][2] = 0.f; sc[c][3] = 0.f; }
#pragma unroll
    for (int c = 0; c < 2; c++) {
      const __bf16* kp = k + (size_t)(b * S_LEN + kv0 + c * 16 + lrow) * (NKV * HD) + kvh * HD + lk;
#pragma unroll
      for (int kk = 0; kk < 4; kk++)
        sc[c] = mfma16(qf[kk], *reinterpret_cast<const bf16x8*>(kp + kk * 32), sc[c]);
    }

    // ---- scale + causal mask + online softmax stats
    float pexp[2][4];
    float es[4];
#pragma unroll
    for (int jj = 0; jj < 4; jj++) {
      int qidx = q0 + lg * 4 + jj;
      float s0 = sc[0][jj] * scale;
      float s1 = sc[1][jj] * scale;
      if (kv0 + lrow > qidx)      s0 = -1e30f;
      if (kv0 + 16 + lrow > qidx) s1 = -1e30f;
      float vv = fmaxf(s0, s1);
      vv = fmaxf(vv, __shfl_xor(vv, 1));
      vv = fmaxf(vv, __shfl_xor(vv, 2));
      vv = fmaxf(vv, __shfl_xor(vv, 4));
      vv = fmaxf(vv, __shfl_xor(vv, 8));
      float mn = fmaxf(m[jj], vv);
      es[jj] = expf(m[jj] - mn);
      m[jj] = mn;
      float p0 = expf(s0 - mn);
      float p1 = expf(s1 - mn);
      pexp[0][jj] = p0; pexp[1][jj] = p1;
      float ps = p0 + p1;
      ps += __shfl_xor(ps, 1);
      ps += __shfl_xor(ps, 2);
      ps += __shfl_xor(ps, 4);
      ps += __shfl_xor(ps, 8);
      ssum[jj] = ssum[jj] * es[jj] + ps;
    }

    __syncthreads();  // protect previous iteration's LDS reads
    // ---- write P tile [16 q][32 kv] as bf16
#pragma unroll
    for (int jj = 0; jj < 4; jj++) {
      Ps[lg * 4 + jj][lrow]      = (__bf16)pexp[0][jj];
      Ps[lg * 4 + jj][16 + lrow] = (__bf16)pexp[1][jj];
    }
    // ---- stage V transposed: Vst[d][kv]
#pragma unroll
    for (int i = 0; i < 8; i++) {
      int kvr = i * 4 + lg;
      int c0 = lrow * 8;
      bf16x8 vv = *reinterpret_cast<const bf16x8*>(
          v + (size_t)(b * S_LEN + kv0 + kvr) * (NKV * HD) + kvh * HD + c0);
#pragma unroll
      for (int e = 0; e < 8; e++) Vst[c0 + e][kvr] = vv[e];
    }
    __syncthreads();

    // ---- PV: A = P (rows=q, k=kv), B = V^T-staged (k=kv, col=d)
    bf16x8 pf = *reinterpret_cast<bf16x8*>(&Ps[lrow][lk]);
#pragma unroll
    for (int n = 0; n < 8; n++) {
      bf16x8 vf = *reinterpret_cast<bf16x8*>(&Vst[n * 16 + lrow][lk]);
      f32x4 t = ov[n];
#pragma unroll
      for (int jj = 0; jj < 4; jj++) t[jj] *= es[jj];
      ov[n] = mfma16(pf, vf, t);
    }
  }

  // ---- epilogue: normalize and store
#pragma unroll
  for (int n = 0; n < 8; n++)
#pragma unroll
    for (int jj = 0; jj < 4; jj++) {
      float val = ov[n][jj] / ssum[jj];
      out[(size_t)(b * S_LEN + q0 + lg * 4 + jj) * (NH * HD) + h * HD + n * 16 + lrow] =
          (__bf16)val;
    }
}

// ---------------------------------------------------------------------------
// Launcher. Workspace layout (bf16):
//   q_buf  [4096][4096]  @ 0         (33554432 B)
//   k_buf  [4096][1024]  @ 33554432  ( 8388608 B)
//   v_buf  [4096][1024]  @ 41943040  ( 8388608 B)
//   a_buf  [4096][4096]  @ 50331648  (33554432 B)
// total 83886080 B of d_ws.
// ---------------------------------------------------------------------------
extern "C" void kernel_launch(void* const* d_in, const int* in_sizes, int n_in,
                              void* d_out, int out_size, void* d_ws, size_t ws_size,
                              hipStream_t stream) {
  const float* hidden = (const float*)d_in[0];
  const int* posids   = (const int*)d_in[1];
  const float* Wq     = (const float*)d_in[2];
  const float* Wk     = (const float*)d_in[3];
  const float* Wv     = (const float*)d_in[4];
  const float* Wo     = (const float*)d_in[5];
  float* out = (float*)d_out;

  char* ws = (char*)d_ws;
  __bf16* q_buf = (__bf16*)(ws + 0);
  __bf16* k_buf = (__bf16*)(ws + 33554432);
  __bf16* v_buf = (__bf16*)(ws + 41943040);
  __bf16* a_buf = (__bf16*)(ws + 50331648);

  const int M = BATCH * S_LEN;  // 4096
  dim3 blk(256);

  gemm_kernel<float, __bf16><<<dim3(HIDDEN / 64, M / 64), blk, 0, stream>>>(
      hidden, Wq, q_buf, M, HIDDEN, HIDDEN);
  gemm_kernel<float, __bf16><<<dim3((NKV * HD) / 64, M / 64), blk, 0, stream>>>(
      hidden, Wk, k_buf, M, NKV * HD, HIDDEN);
  gemm_kernel<float, __bf16><<<dim3((NKV * HD) / 64, M / 64), blk, 0, stream>>>(
      hidden, Wv, v_buf, M, NKV * HD, HIDDEN);

  rope_kernel<<<dim3(NH + NKV, M), dim3(64), 0, stream>>>(q_buf, k_buf, posids);

  attn_kernel<<<dim3(S_LEN / 16, NH, BATCH), dim3(64), 0, stream>>>(
      q_buf, k_buf, v_buf, a_buf);

  gemm_kernel<__bf16, float><<<dim3(HIDDEN / 64, M / 64), blk, 0, stream>>>(
      a_buf, Wo, out, M, HIDDEN, HIDDEN);
}

// Round 2
// 1394.419 us; speedup vs baseline: 1.8132x; 1.8132x over previous
//
#include <hip/hip_runtime.h>
#include <hip/hip_bf16.h>
#include <math.h>

#define HIDDEN 4096
#define NH 32
#define NKV 8
#define HD 128
#define S_LEN 2048
#define BATCH 2
#define MROWS (BATCH * S_LEN)  // 4096

typedef __attribute__((ext_vector_type(8))) __bf16 bf16x8;
typedef __attribute__((ext_vector_type(4))) float f32x4;

__device__ __forceinline__ f32x4 mfma16(bf16x8 a, bf16x8 b, f32x4 c) {
  return __builtin_amdgcn_mfma_f32_16x16x32_bf16(a, b, c, 0, 0, 0);
}

// async global->LDS, 16B per lane. LDS dest must be wave-uniform base; HW
// writes base + lane*16.
__device__ __forceinline__ void gload16(const __bf16* g, __bf16* l) {
  __builtin_amdgcn_global_load_lds(
      (const __attribute__((address_space(1))) void*)g,
      (__attribute__((address_space(3))) void*)l, 16, 0, 0);
}

// ---------------------------------------------------------------------------
// fp32 -> bf16 elementwise convert (vectorized)
// ---------------------------------------------------------------------------
__global__ __launch_bounds__(256) void cvt_kernel(const float* __restrict__ in,
                                                  __bf16* __restrict__ out, int n) {
  int i = (blockIdx.x * 256 + threadIdx.x) * 8;
  if (i >= n) return;
  float4 a = *reinterpret_cast<const float4*>(in + i);
  float4 b = *reinterpret_cast<const float4*>(in + i + 4);
  bf16x8 t;
  t[0] = (__bf16)a.x; t[1] = (__bf16)a.y; t[2] = (__bf16)a.z; t[3] = (__bf16)a.w;
  t[4] = (__bf16)b.x; t[5] = (__bf16)b.y; t[6] = (__bf16)b.z; t[7] = (__bf16)b.w;
  *reinterpret_cast<bf16x8*>(out + i) = t;
}

// ---------------------------------------------------------------------------
// Transpose + convert: out[c][r] = (bf16) in[r][c].  in: [R][C] fp32.
// block (32,8), grid (C/32, R/32).
// ---------------------------------------------------------------------------
__global__ __launch_bounds__(256) void tcvt_f32(const float* __restrict__ in,
                                                __bf16* __restrict__ out,
                                                int R, int C) {
  __shared__ float t[32][33];
  int tx = threadIdx.x, ty = threadIdx.y;
  int r0 = blockIdx.y * 32, c0 = blockIdx.x * 32;
#pragma unroll
  for (int i = 0; i < 4; i++)
    t[ty + i * 8][tx] = in[(size_t)(r0 + ty + i * 8) * C + c0 + tx];
  __syncthreads();
#pragma unroll
  for (int i = 0; i < 4; i++)
    out[(size_t)(c0 + ty + i * 8) * R + r0 + tx] = (__bf16)t[tx][ty + i * 8];
}

// ---------------------------------------------------------------------------
// V transpose: v_buf [B*S][NKV*HD] bf16 -> vt [B*NKV][HD][S] bf16.
// grid (HD/32, S/32, B*NKV), block (32,8).
// ---------------------------------------------------------------------------
__global__ __launch_bounds__(256) void tvt_kernel(const __bf16* __restrict__ v,
                                                  __bf16* __restrict__ vt) {
  __shared__ __bf16 t[32][33];
  int tx = threadIdx.x, ty = threadIdx.y;
  int z = blockIdx.z;
  int b = z >> 3, kvh = z & 7;
  int kv0 = blockIdx.y * 32, d0 = blockIdx.x * 32;
#pragma unroll
  for (int i = 0; i < 4; i++)
    t[ty + i * 8][tx] =
        v[(size_t)(b * S_LEN + kv0 + ty + i * 8) * (NKV * HD) + kvh * HD + d0 + tx];
  __syncthreads();
#pragma unroll
  for (int i = 0; i < 4; i++)
    vt[((size_t)z * HD + d0 + ty + i * 8) * S_LEN + kv0 + tx] = t[tx][ty + i * 8];
}

// ---------------------------------------------------------------------------
// GEMM (m97 structure): C[M,N] = A[M,K] * Bt[N,K]^T, all bf16 in, CT out.
// 128x128 tile, BK=64, 4 waves (2x2 of 64x64), global_load_lds 16B staging,
// XCD-swizzled 1-D grid (nwg % 8 == 0 for all our shapes).
// ---------------------------------------------------------------------------
template<typename CT>
__global__ __launch_bounds__(256) void gemm_bt(const __bf16* __restrict__ A,
                                               const __bf16* __restrict__ Bt,
                                               CT* __restrict__ C,
                                               int M, int N, int K, int nbx) {
  __shared__ __bf16 As[128 * 64];
  __shared__ __bf16 Bs[128 * 64];
  int tid = threadIdx.x;
  int l = tid & 63, w = tid >> 6;

  int nwg = gridDim.x;
  int qq = nwg >> 3;
  int bid = blockIdx.x;
  int swz = (bid & 7) * qq + (bid >> 3);
  int bx = swz % nbx, by = swz / nbx;
  int m0 = by * 128, n0 = bx * 128;
  int wm = (w >> 1) * 64, wn = (w & 1) * 64;
  int lrow = l & 15, lg = l >> 4;

  f32x4 acc[4][4];
#pragma unroll
  for (int i = 0; i < 4; i++)
#pragma unroll
    for (int j = 0; j < 4; j++) {
      acc[i][j][0] = 0.f; acc[i][j][1] = 0.f; acc[i][j][2] = 0.f; acc[i][j][3] = 0.f;
    }

  int srow = tid >> 3;         // 0..31
  int scol = (tid & 7) * 8;    // 0..56
  const __bf16* Abase = A + (size_t)(m0 + srow) * K + scol;
  const __bf16* Bbase = Bt + (size_t)(n0 + srow) * K + scol;

  for (int k0 = 0; k0 < K; k0 += 64) {
#pragma unroll
    for (int p = 0; p < 4; p++)
      gload16(Abase + (size_t)p * 32 * K + k0, As + p * 2048 + w * 512);
#pragma unroll
    for (int p = 0; p < 4; p++)
      gload16(Bbase + (size_t)p * 32 * K + k0, Bs + p * 2048 + w * 512);
    __syncthreads();

#pragma unroll
    for (int kk = 0; kk < 2; kk++) {
      bf16x8 af[4], bfr[4];
#pragma unroll
      for (int i = 0; i < 4; i++)
        af[i] = *reinterpret_cast<const bf16x8*>(As + (wm + i * 16 + lrow) * 64 + kk * 32 + lg * 8);
#pragma unroll
      for (int i = 0; i < 4; i++)
        bfr[i] = *reinterpret_cast<const bf16x8*>(Bs + (wn + i * 16 + lrow) * 64 + kk * 32 + lg * 8);
#pragma unroll
      for (int i = 0; i < 4; i++)
#pragma unroll
        for (int j = 0; j < 4; j++)
          acc[i][j] = mfma16(af[i], bfr[j], acc[i][j]);
    }
    __syncthreads();
  }

#pragma unroll
  for (int i = 0; i < 4; i++)
#pragma unroll
    for (int j = 0; j < 4; j++)
#pragma unroll
      for (int jj = 0; jj < 4; jj++) {
        int row = m0 + wm + i * 16 + lg * 4 + jj;
        int col = n0 + wn + j * 16 + lrow;
        C[(size_t)row * N + col] = (CT)acc[i][j][jj];
      }
}

// ---------------------------------------------------------------------------
// RoPE, in-place on bf16 q/k. grid (NH+NKV, B*S), block 64.
// ---------------------------------------------------------------------------
__global__ __launch_bounds__(64) void rope_kernel(__bf16* __restrict__ qb,
                                                  __bf16* __restrict__ kb,
                                                  const int* __restrict__ pos) {
  int pair = threadIdx.x;   // 0..63
  int head = blockIdx.x;
  int row = blockIdx.y;
  int p = pos[row];
  // inv_freq = 10000^(-pair/64) = 2^(-pair*log2(10000)/64)
  float inv = exp2f(-0.20762050f * (float)pair);
  float ang = (float)p * inv;
  float s, c;
  __sincosf(ang, &s, &c);
  __bf16* base;
  if (head < NH) base = qb + (size_t)row * (NH * HD) + head * HD;
  else           base = kb + (size_t)row * (NKV * HD) + (head - NH) * HD;
  float x1 = (float)base[pair];
  float x2 = (float)base[pair + 64];
  base[pair]      = (__bf16)(x1 * c - x2 * s);
  base[pair + 64] = (__bf16)(x2 * c + x1 * s);
}

// ---------------------------------------------------------------------------
// Flash attention, causal, GQA. 4 waves/block, each wave an independent 32-row
// q tile (q-tiles strided so per-block work is balanced). K and V^T read
// directly from global (L2/L3 resident). P through per-wave-private LDS.
// Softmax in exp2 domain; scale*log2e pre-folded into Q.
// ---------------------------------------------------------------------------
__global__ __launch_bounds__(256) void attn_kernel(const __bf16* __restrict__ q,
                                                   const __bf16* __restrict__ k,
                                                   const __bf16* __restrict__ vt,
                                                   __bf16* __restrict__ out) {
  __shared__ __bf16 Ps[4][32][36];
  int tid = threadIdx.x;
  int l = tid & 63, w = tid >> 6;
  int h = blockIdx.y, b = blockIdx.z;
  int kvh = h >> 2;
  int q0 = (blockIdx.x + w * 16) * 32;
  int lrow = l & 15, lg = l >> 4;
  const float SCL = 0.08838834764831845f * 1.4426950408889634f;  // 1/sqrt(128)*log2e

  // Q fragments, pre-scaled
  bf16x8 qf[2][4];
#pragma unroll
  for (int mi = 0; mi < 2; mi++) {
    const __bf16* qp = q + (size_t)(b * S_LEN + q0 + mi * 16 + lrow) * HIDDEN + h * HD + lg * 8;
#pragma unroll
    for (int kk = 0; kk < 4; kk++) {
      bf16x8 t = *reinterpret_cast<const bf16x8*>(qp + kk * 32);
#pragma unroll
      for (int e = 0; e < 8; e++) t[e] = (__bf16)((float)t[e] * SCL);
      qf[mi][kk] = t;
    }
  }

  f32x4 ov[2][8];
#pragma unroll
  for (int mi = 0; mi < 2; mi++)
#pragma unroll
    for (int n = 0; n < 8; n++) {
      ov[mi][n][0] = 0.f; ov[mi][n][1] = 0.f; ov[mi][n][2] = 0.f; ov[mi][n][3] = 0.f;
    }
  float m[2][4], ssum[2][4];
#pragma unroll
  for (int mi = 0; mi < 2; mi++)
#pragma unroll
    for (int jj = 0; jj < 4; jj++) { m[mi][jj] = -3.0e38f; ssum[mi][jj] = 0.f; }

  const __bf16* kbase = k + (size_t)(b * S_LEN) * (NKV * HD) + kvh * HD;
  const __bf16* vbase = vt + ((size_t)(b * NKV + kvh) * HD) * S_LEN;

  for (int kv0 = 0; kv0 <= q0; kv0 += 32) {
    // ---- QK^T: scores for 32 q rows x 32 kv cols
    f32x4 sc[2][2];
#pragma unroll
    for (int mi = 0; mi < 2; mi++)
#pragma unroll
      for (int c = 0; c < 2; c++) {
        sc[mi][c][0] = 0.f; sc[mi][c][1] = 0.f; sc[mi][c][2] = 0.f; sc[mi][c][3] = 0.f;
      }
#pragma unroll
    for (int c = 0; c < 2; c++) {
      const __bf16* kp = kbase + (size_t)(kv0 + c * 16 + lrow) * (NKV * HD) + lg * 8;
#pragma unroll
      for (int kk = 0; kk < 4; kk++) {
        bf16x8 kf = *reinterpret_cast<const bf16x8*>(kp + kk * 32);
        sc[0][c] = mfma16(qf[0][kk], kf, sc[0][c]);
        sc[1][c] = mfma16(qf[1][kk], kf, sc[1][c]);
      }
    }

    // ---- online softmax (exp2 domain), write P to per-wave LDS
    float es[2][4];
    bool anyr = false;
#pragma unroll
    for (int mi = 0; mi < 2; mi++)
#pragma unroll
      for (int jj = 0; jj < 4; jj++) {
        int qidx = q0 + mi * 16 + lg * 4 + jj;
        float s0 = sc[mi][0][jj];
        float s1 = sc[mi][1][jj];
        if (kv0 + lrow > qidx)      s0 = -3.0e38f;
        if (kv0 + 16 + lrow > qidx) s1 = -3.0e38f;
        float r = fmaxf(s0, s1);
        r = fmaxf(r, __shfl_xor(r, 1));
        r = fmaxf(r, __shfl_xor(r, 2));
        r = fmaxf(r, __shfl_xor(r, 4));
        r = fmaxf(r, __shfl_xor(r, 8));
        float mo = m[mi][jj];
        float mn = fmaxf(mo, r);
        float e = exp2f(mo - mn);
        es[mi][jj] = e;
        anyr |= (mn > mo);
        m[mi][jj] = mn;
        float p0 = exp2f(s0 - mn);
        float p1 = exp2f(s1 - mn);
        ssum[mi][jj] = ssum[mi][jj] * e + p0 + p1;   // per-lane partial row sum
        Ps[w][mi * 16 + lg * 4 + jj][lrow]      = (__bf16)p0;
        Ps[w][mi * 16 + lg * 4 + jj][16 + lrow] = (__bf16)p1;
      }
    if (__any(anyr)) {
#pragma unroll
      for (int mi = 0; mi < 2; mi++)
#pragma unroll
        for (int n = 0; n < 8; n++)
#pragma unroll
          for (int jj = 0; jj < 4; jj++) ov[mi][n][jj] *= es[mi][jj];
    }

    // ---- PV: A = P (from LDS), B = Vt fragment (contiguous 16B global read)
    bf16x8 pf0 = *reinterpret_cast<const bf16x8*>(&Ps[w][lrow][lg * 8]);
    bf16x8 pf1 = *reinterpret_cast<const bf16x8*>(&Ps[w][16 + lrow][lg * 8]);
#pragma unroll
    for (int n = 0; n < 8; n++) {
      bf16x8 vf = *reinterpret_cast<const bf16x8*>(
          vbase + (size_t)(n * 16 + lrow) * S_LEN + kv0 + lg * 8);
      ov[0][n] = mfma16(pf0, vf, ov[0][n]);
      ov[1][n] = mfma16(pf1, vf, ov[1][n]);
    }
  }

  // ---- epilogue: finish row sums, normalize, store
  float rinv[2][4];
#pragma unroll
  for (int mi = 0; mi < 2; mi++)
#pragma unroll
    for (int jj = 0; jj < 4; jj++) {
      float s = ssum[mi][jj];
      s += __shfl_xor(s, 1);
      s += __shfl_xor(s, 2);
      s += __shfl_xor(s, 4);
      s += __shfl_xor(s, 8);
      rinv[mi][jj] = 1.0f / s;
    }
#pragma unroll
  for (int mi = 0; mi < 2; mi++)
#pragma unroll
    for (int n = 0; n < 8; n++)
#pragma unroll
      for (int jj = 0; jj < 4; jj++) {
        out[(size_t)(b * S_LEN + q0 + mi * 16 + lg * 4 + jj) * HIDDEN + h * HD + n * 16 + lrow] =
            (__bf16)(ov[mi][n][jj] * rinv[mi][jj]);
      }
}

// ---------------------------------------------------------------------------
// Workspace layout (bytes):
//   h_bf / a_buf (aliased) @ 0          33554432   bf16 [4096][4096]
//   Wt_big               @ 33554432     33554432   bf16 [4096][4096] (Wq^T then Wo^T)
//   Wk_t                 @ 67108864      8388608   bf16 [1024][4096]
//   Wv_t                 @ 75497472      8388608   bf16 [1024][4096]
//   q_buf                @ 83886080     33554432   bf16 [4096][4096]
//   k_buf                @ 117440512     8388608   bf16 [4096][1024]
//   v_buf                @ 125829120     8388608   bf16 [4096][1024]
//   vt_buf               @ 134217728     8388608   bf16 [16][128][2048]
// total 142606336 B
// ---------------------------------------------------------------------------
extern "C" void kernel_launch(void* const* d_in, const int* in_sizes, int n_in,
                              void* d_out, int out_size, void* d_ws, size_t ws_size,
                              hipStream_t stream) {
  const float* hidden = (const float*)d_in[0];
  const int* posids   = (const int*)d_in[1];
  const float* Wq     = (const float*)d_in[2];
  const float* Wk     = (const float*)d_in[3];
  const float* Wv     = (const float*)d_in[4];
  const float* Wo     = (const float*)d_in[5];
  float* out = (float*)d_out;

  char* ws = (char*)d_ws;
  __bf16* h_bf   = (__bf16*)(ws + 0);
  __bf16* a_buf  = h_bf;  // aliased: hidden last read before attn writes it
  __bf16* Wt_big = (__bf16*)(ws + 33554432);
  __bf16* Wk_t   = (__bf16*)(ws + 67108864);
  __bf16* Wv_t   = (__bf16*)(ws + 75497472);
  __bf16* q_buf  = (__bf16*)(ws + 83886080);
  __bf16* k_buf  = (__bf16*)(ws + 117440512);
  __bf16* v_buf  = (__bf16*)(ws + 125829120);
  __bf16* vt_buf = (__bf16*)(ws + 134217728);

  dim3 b256(256), b328(32, 8);

  // 1. hidden -> bf16
  cvt_kernel<<<dim3(MROWS * HIDDEN / (256 * 8)), b256, 0, stream>>>(hidden, h_bf, MROWS * HIDDEN);

  // 2-3. Wq^T, Q = h @ Wq
  tcvt_f32<<<dim3(HIDDEN / 32, HIDDEN / 32), b328, 0, stream>>>(Wq, Wt_big, HIDDEN, HIDDEN);
  gemm_bt<__bf16><<<dim3((HIDDEN / 128) * (MROWS / 128)), b256, 0, stream>>>(
      h_bf, Wt_big, q_buf, MROWS, HIDDEN, HIDDEN, HIDDEN / 128);

  // 4-5. Wk^T, K
  tcvt_f32<<<dim3((NKV * HD) / 32, HIDDEN / 32), b328, 0, stream>>>(Wk, Wk_t, HIDDEN, NKV * HD);
  gemm_bt<__bf16><<<dim3(((NKV * HD) / 128) * (MROWS / 128)), b256, 0, stream>>>(
      h_bf, Wk_t, k_buf, MROWS, NKV * HD, HIDDEN, (NKV * HD) / 128);

  // 6-7. Wv^T, V
  tcvt_f32<<<dim3((NKV * HD) / 32, HIDDEN / 32), b328, 0, stream>>>(Wv, Wv_t, HIDDEN, NKV * HD);
  gemm_bt<__bf16><<<dim3(((NKV * HD) / 128) * (MROWS / 128)), b256, 0, stream>>>(
      h_bf, Wv_t, v_buf, MROWS, NKV * HD, HIDDEN, (NKV * HD) / 128);

  // 8. RoPE on q,k
  rope_kernel<<<dim3(NH + NKV, MROWS), dim3(64), 0, stream>>>(q_buf, k_buf, posids);

  // 9. V^T
  tvt_kernel<<<dim3(HD / 32, S_LEN / 32, BATCH * NKV), b328, 0, stream>>>(v_buf, vt_buf);

  // 10. attention -> a_buf (overwrites h_bf region; h_bf no longer needed)
  attn_kernel<<<dim3(S_LEN / 32 / 4, NH, BATCH), b256, 0, stream>>>(q_buf, k_buf, vt_buf, a_buf);

  // 11-12. Wo^T, out = a @ Wo (fp32 out)
  tcvt_f32<<<dim3(HIDDEN / 32, HIDDEN / 32), b328, 0, stream>>>(Wo, Wt_big, HIDDEN, HIDDEN);
  gemm_bt<float><<<dim3((HIDDEN / 128) * (MROWS / 128)), b256, 0, stream>>>(
      a_buf, Wt_big, out, MROWS, HIDDEN, HIDDEN, HIDDEN / 128);
}

// Round 3
// 826.611 us; speedup vs baseline: 3.0587x; 1.6869x over previous
//
#include <hip/hip_runtime.h>
#include <hip/hip_bf16.h>
#include <math.h>

#define HIDDEN 4096
#define NH 32
#define NKV 8
#define HD 128
#define S_LEN 2048
#define BATCH 2
#define MROWS (BATCH * S_LEN)  // 4096

typedef __attribute__((ext_vector_type(8))) __bf16 bf16x8;
typedef __attribute__((ext_vector_type(4))) float f32x4;

__device__ __forceinline__ f32x4 mfma16(bf16x8 a, bf16x8 b, f32x4 c) {
  return __builtin_amdgcn_mfma_f32_16x16x32_bf16(a, b, c, 0, 0, 0);
}

// async global->LDS, 16B per lane. LDS dest must be wave-uniform base; HW
// writes base + lane*16.
__device__ __forceinline__ void gload16(const __bf16* g, __bf16* l) {
  __builtin_amdgcn_global_load_lds(
      (const __attribute__((address_space(1))) void*)g,
      (__attribute__((address_space(3))) void*)l, 16, 0, 0);
}

// ---------------------------------------------------------------------------
// fp32 -> bf16 elementwise convert (vectorized)
// ---------------------------------------------------------------------------
__global__ __launch_bounds__(256) void cvt_kernel(const float* __restrict__ in,
                                                  __bf16* __restrict__ out, int n) {
  int i = (blockIdx.x * 256 + threadIdx.x) * 8;
  if (i >= n) return;
  float4 a = *reinterpret_cast<const float4*>(in + i);
  float4 b = *reinterpret_cast<const float4*>(in + i + 4);
  bf16x8 t;
  t[0] = (__bf16)a.x; t[1] = (__bf16)a.y; t[2] = (__bf16)a.z; t[3] = (__bf16)a.w;
  t[4] = (__bf16)b.x; t[5] = (__bf16)b.y; t[6] = (__bf16)b.z; t[7] = (__bf16)b.w;
  *reinterpret_cast<bf16x8*>(out + i) = t;
}

// ---------------------------------------------------------------------------
// Transpose + convert: out[c][r] = (bf16) in[r][c].  in: [R][C] fp32.
// block (32,8), grid (C/32, R/32).
// ---------------------------------------------------------------------------
__global__ __launch_bounds__(256) void tcvt_f32(const float* __restrict__ in,
                                                __bf16* __restrict__ out,
                                                int R, int C) {
  __shared__ float t[32][33];
  int tx = threadIdx.x, ty = threadIdx.y;
  int r0 = blockIdx.y * 32, c0 = blockIdx.x * 32;
#pragma unroll
  for (int i = 0; i < 4; i++)
    t[ty + i * 8][tx] = in[(size_t)(r0 + ty + i * 8) * C + c0 + tx];
  __syncthreads();
#pragma unroll
  for (int i = 0; i < 4; i++)
    out[(size_t)(c0 + ty + i * 8) * R + r0 + tx] = (__bf16)t[tx][ty + i * 8];
}

// ---------------------------------------------------------------------------
// V transpose: v_buf [B*S][NKV*HD] bf16 -> vt [B*NKV][HD][S] bf16.
// grid (HD/32, S/32, B*NKV), block (32,8).
// ---------------------------------------------------------------------------
__global__ __launch_bounds__(256) void tvt_kernel(const __bf16* __restrict__ v,
                                                  __bf16* __restrict__ vt) {
  __shared__ __bf16 t[32][33];
  int tx = threadIdx.x, ty = threadIdx.y;
  int z = blockIdx.z;
  int b = z >> 3, kvh = z & 7;
  int kv0 = blockIdx.y * 32, d0 = blockIdx.x * 32;
#pragma unroll
  for (int i = 0; i < 4; i++)
    t[ty + i * 8][tx] =
        v[(size_t)(b * S_LEN + kv0 + ty + i * 8) * (NKV * HD) + kvh * HD + d0 + tx];
  __syncthreads();
#pragma unroll
  for (int i = 0; i < 4; i++)
    vt[((size_t)z * HD + d0 + ty + i * 8) * S_LEN + kv0 + tx] = t[tx][ty + i * 8];
}

// ---------------------------------------------------------------------------
// GEMM (m97 structure): C[M,N] = A[M,K] * Bt[N,K]^T, all bf16 in, CT out.
// 128x128 tile, BK=64, 4 waves (2x2 of 64x64), global_load_lds 16B staging,
// XCD-swizzled 1-D grid (nwg % 8 == 0 for all our shapes).
// ---------------------------------------------------------------------------
template<typename CT>
__global__ __launch_bounds__(256) void gemm_bt(const __bf16* __restrict__ A,
                                               const __bf16* __restrict__ Bt,
                                               CT* __restrict__ C,
                                               int M, int N, int K, int nbx) {
  __shared__ __bf16 As[128 * 64];
  __shared__ __bf16 Bs[128 * 64];
  int tid = threadIdx.x;
  int l = tid & 63, w = tid >> 6;

  int nwg = gridDim.x;
  int qq = nwg >> 3;
  int bid = blockIdx.x;
  int swz = (bid & 7) * qq + (bid >> 3);
  int bx = swz % nbx, by = swz / nbx;
  int m0 = by * 128, n0 = bx * 128;
  int wm = (w >> 1) * 64, wn = (w & 1) * 64;
  int lrow = l & 15, lg = l >> 4;

  f32x4 acc[4][4];
#pragma unroll
  for (int i = 0; i < 4; i++)
#pragma unroll
    for (int j = 0; j < 4; j++) {
      acc[i][j][0] = 0.f; acc[i][j][1] = 0.f; acc[i][j][2] = 0.f; acc[i][j][3] = 0.f;
    }

  int srow = tid >> 3;         // 0..31
  int scol = (tid & 7) * 8;    // 0..56
  const __bf16* Abase = A + (size_t)(m0 + srow) * K + scol;
  const __bf16* Bbase = Bt + (size_t)(n0 + srow) * K + scol;

  for (int k0 = 0; k0 < K; k0 += 64) {
#pragma unroll
    for (int p = 0; p < 4; p++)
      gload16(Abase + (size_t)p * 32 * K + k0, As + p * 2048 + w * 512);
#pragma unroll
    for (int p = 0; p < 4; p++)
      gload16(Bbase + (size_t)p * 32 * K + k0, Bs + p * 2048 + w * 512);
    __syncthreads();

#pragma unroll
    for (int kk = 0; kk < 2; kk++) {
      bf16x8 af[4], bfr[4];
#pragma unroll
      for (int i = 0; i < 4; i++)
        af[i] = *reinterpret_cast<const bf16x8*>(As + (wm + i * 16 + lrow) * 64 + kk * 32 + lg * 8);
#pragma unroll
      for (int i = 0; i < 4; i++)
        bfr[i] = *reinterpret_cast<const bf16x8*>(Bs + (wn + i * 16 + lrow) * 64 + kk * 32 + lg * 8);
#pragma unroll
      for (int i = 0; i < 4; i++)
#pragma unroll
        for (int j = 0; j < 4; j++)
          acc[i][j] = mfma16(af[i], bfr[j], acc[i][j]);
    }
    __syncthreads();
  }

#pragma unroll
  for (int i = 0; i < 4; i++)
#pragma unroll
    for (int j = 0; j < 4; j++)
#pragma unroll
      for (int jj = 0; jj < 4; jj++) {
        int row = m0 + wm + i * 16 + lg * 4 + jj;
        int col = n0 + wn + j * 16 + lrow;
        C[(size_t)row * N + col] = (CT)acc[i][j][jj];
      }
}

// ---------------------------------------------------------------------------
// RoPE, in-place on bf16 q/k. grid (NH+NKV, B*S), block 64.
// ---------------------------------------------------------------------------
__global__ __launch_bounds__(64) void rope_kernel(__bf16* __restrict__ qb,
                                                  __bf16* __restrict__ kb,
                                                  const int* __restrict__ pos) {
  int pair = threadIdx.x;   // 0..63
  int head = blockIdx.x;
  int row = blockIdx.y;
  int p = pos[row];
  float inv = exp2f(-0.20762050f * (float)pair);   // 10000^(-pair/64)
  float ang = (float)p * inv;
  float s, c;
  __sincosf(ang, &s, &c);
  __bf16* base;
  if (head < NH) base = qb + (size_t)row * (NH * HD) + head * HD;
  else           base = kb + (size_t)row * (NKV * HD) + (head - NH) * HD;
  float x1 = (float)base[pair];
  float x2 = (float)base[pair + 64];
  base[pair]      = (__bf16)(x1 * c - x2 * s);
  base[pair + 64] = (__bf16)(x2 * c + x1 * s);
}

// ---------------------------------------------------------------------------
// Flash attention, causal, GQA. 8-wave cooperative blocks (m214-style):
// block = 256 q rows (wave w owns rows qblk*256 + w*32 .. +32), KVBLK=64.
// K tile [64][128] and V^T tile [128][64] reg-staged into LDS with XOR
// swizzle (byte ^= (row&7)<<4) so b128 fragment reads are conflict-free.
// T14 split: global loads for tile t+1 issued before compute of tile t,
// ds_write after the post-compute barrier. Softmax in exp2 domain, P via
// per-wave padded LDS. Heavy q-blocks dispatched first.
// ---------------------------------------------------------------------------
__global__ __launch_bounds__(512) void attn_kernel(const __bf16* __restrict__ q,
                                                   const __bf16* __restrict__ k,
                                                   const __bf16* __restrict__ vt,
                                                   __bf16* __restrict__ out) {
  __shared__ __bf16 Ks[64 * 128];      // [kv][d], swizzled, 16 KB
  __shared__ __bf16 Vs[128 * 64];      // [d][kv], swizzled, 16 KB
  __shared__ __bf16 Ps[8][32][68];     // per-wave P, padded, 34 KB

  int tid = threadIdx.x;
  int l = tid & 63, w = tid >> 6;
  int bid = blockIdx.x;
  int qblk = 7 - (bid >> 6);           // heavy blocks first
  int rem = bid & 63;
  int h = rem & 31, b = rem >> 5;
  int kvh = h >> 2;
  int q0w = qblk * 256 + w * 32;
  int lrow = l & 15, lg = l >> 4;
  int sw = (lrow & 7) << 4;
  const float SCL = 0.08838834764831845f * 1.4426950408889634f;  // 1/sqrt(128)*log2e

  const __bf16* kbase = k + (size_t)(b * S_LEN) * (NKV * HD) + kvh * HD;
  const __bf16* vbase = vt + ((size_t)(b * NKV + kvh) * HD) * S_LEN;

  // staging assignment: each thread owns two 16B chunks of each tile
  int krow = tid >> 3;                 // 0..63
  int kslot = (tid & 7) * 2;           // 0..14
  int vrow = tid >> 2;                 // 0..127
  int vslot = (tid & 3) * 2;           // 0..6
  char* KsB = (char*)Ks;
  char* VsB = (char*)Vs;
  int koff0 = krow * 256 + ((kslot * 16) ^ ((krow & 7) << 4));
  int koff1 = krow * 256 + (((kslot + 1) * 16) ^ ((krow & 7) << 4));
  int voff0 = vrow * 128 + ((vslot * 16) ^ ((vrow & 7) << 4));
  int voff1 = vrow * 128 + (((vslot + 1) * 16) ^ ((vrow & 7) << 4));
  const __bf16* kg = kbase + (size_t)krow * (NKV * HD) + kslot * 8;
  const __bf16* vg = vbase + (size_t)vrow * S_LEN + vslot * 8;

  // Q fragments, pre-scaled
  bf16x8 qf[2][4];
#pragma unroll
  for (int mi = 0; mi < 2; mi++) {
    const __bf16* qp = q + (size_t)(b * S_LEN + q0w + mi * 16 + lrow) * HIDDEN + h * HD + lg * 8;
#pragma unroll
    for (int kk = 0; kk < 4; kk++) {
      bf16x8 t = *reinterpret_cast<const bf16x8*>(qp + kk * 32);
#pragma unroll
      for (int e = 0; e < 8; e++) t[e] = (__bf16)((float)t[e] * SCL);
      qf[mi][kk] = t;
    }
  }

  f32x4 ov[2][8];
#pragma unroll
  for (int mi = 0; mi < 2; mi++)
#pragma unroll
    for (int n = 0; n < 8; n++) {
      ov[mi][n][0] = 0.f; ov[mi][n][1] = 0.f; ov[mi][n][2] = 0.f; ov[mi][n][3] = 0.f;
    }
  float m[2][4], ssum[2][4];
#pragma unroll
  for (int mi = 0; mi < 2; mi++)
#pragma unroll
    for (int jj = 0; jj < 4; jj++) { m[mi][jj] = -3.0e38f; ssum[mi][jj] = 0.f; }

  int nt = 4 * qblk + 4;
  bf16x8 kr0, kr1, vr0, vr1;

  // prologue: stage tile 0
  kr0 = *reinterpret_cast<const bf16x8*>(kg);
  kr1 = *reinterpret_cast<const bf16x8*>(kg + 8);
  vr0 = *reinterpret_cast<const bf16x8*>(vg);
  vr1 = *reinterpret_cast<const bf16x8*>(vg + 8);
  *reinterpret_cast<bf16x8*>(KsB + koff0) = kr0;
  *reinterpret_cast<bf16x8*>(KsB + koff1) = kr1;
  *reinterpret_cast<bf16x8*>(VsB + voff0) = vr0;
  *reinterpret_cast<bf16x8*>(VsB + voff1) = vr1;
  __syncthreads();

  for (int t = 0;; t++) {
    int kv0 = t * 64;
    bool more = (t + 1 < nt);
    // issue next tile's global loads early (latency hides under compute)
    if (more) {
      int kvn = kv0 + 64;
      kr0 = *reinterpret_cast<const bf16x8*>(kg + (size_t)kvn * (NKV * HD));
      kr1 = *reinterpret_cast<const bf16x8*>(kg + (size_t)kvn * (NKV * HD) + 8);
      vr0 = *reinterpret_cast<const bf16x8*>(vg + kvn);
      vr1 = *reinterpret_cast<const bf16x8*>(vg + kvn + 8);
    }

    bool active = (kv0 <= q0w + 31);
    if (active) {
      // ---- QK^T from swizzled LDS: 32 q rows x 64 kv cols
      f32x4 sc[2][4];
#pragma unroll
      for (int mi = 0; mi < 2; mi++)
#pragma unroll
        for (int c = 0; c < 4; c++) {
          sc[mi][c][0] = 0.f; sc[mi][c][1] = 0.f; sc[mi][c][2] = 0.f; sc[mi][c][3] = 0.f;
        }
#pragma unroll
      for (int c = 0; c < 4; c++) {
        int rb = (c * 16 + lrow) * 256;
#pragma unroll
        for (int kk = 0; kk < 4; kk++) {
          bf16x8 kf = *reinterpret_cast<const bf16x8*>(KsB + rb + ((kk * 64 + lg * 16) ^ sw));
          sc[0][c] = mfma16(qf[0][kk], kf, sc[0][c]);
          sc[1][c] = mfma16(qf[1][kk], kf, sc[1][c]);
        }
      }

      // ---- online softmax (exp2 domain)
      bool bound = (kv0 + 64 > q0w);
      float es[2][4];
      bool anyr = false;
#pragma unroll
      for (int mi = 0; mi < 2; mi++)
#pragma unroll
        for (int jj = 0; jj < 4; jj++) {
          int qidx = q0w + mi * 16 + lg * 4 + jj;
          float s0 = sc[mi][0][jj], s1 = sc[mi][1][jj];
          float s2 = sc[mi][2][jj], s3 = sc[mi][3][jj];
          if (bound) {
            if (kv0 + lrow > qidx)      s0 = -3.0e38f;
            if (kv0 + 16 + lrow > qidx) s1 = -3.0e38f;
            if (kv0 + 32 + lrow > qidx) s2 = -3.0e38f;
            if (kv0 + 48 + lrow > qidx) s3 = -3.0e38f;
          }
          float r = fmaxf(fmaxf(s0, s1), fmaxf(s2, s3));
          r = fmaxf(r, __shfl_xor(r, 1));
          r = fmaxf(r, __shfl_xor(r, 2));
          r = fmaxf(r, __shfl_xor(r, 4));
          r = fmaxf(r, __shfl_xor(r, 8));
          float mo = m[mi][jj];
          float mn = fmaxf(mo, r);
          float e = exp2f(mo - mn);
          es[mi][jj] = e;
          anyr |= (mn > mo);
          m[mi][jj] = mn;
          float p0 = exp2f(s0 - mn), p1 = exp2f(s1 - mn);
          float p2 = exp2f(s2 - mn), p3 = exp2f(s3 - mn);
          ssum[mi][jj] = ssum[mi][jj] * e + ((p0 + p1) + (p2 + p3));
          int pr = mi * 16 + lg * 4 + jj;
          Ps[w][pr][lrow]      = (__bf16)p0;
          Ps[w][pr][16 + lrow] = (__bf16)p1;
          Ps[w][pr][32 + lrow] = (__bf16)p2;
          Ps[w][pr][48 + lrow] = (__bf16)p3;
        }
      if (__any(anyr)) {
#pragma unroll
        for (int mi = 0; mi < 2; mi++)
#pragma unroll
          for (int n = 0; n < 8; n++)
#pragma unroll
            for (int jj = 0; jj < 4; jj++) ov[mi][n][jj] *= es[mi][jj];
      }

      // ---- PV from swizzled LDS
#pragma unroll
      for (int kvs = 0; kvs < 2; kvs++) {
        bf16x8 pf0 = *reinterpret_cast<const bf16x8*>(&Ps[w][lrow][kvs * 32 + lg * 8]);
        bf16x8 pf1 = *reinterpret_cast<const bf16x8*>(&Ps[w][16 + lrow][kvs * 32 + lg * 8]);
#pragma unroll
        for (int n = 0; n < 8; n++) {
          bf16x8 vf = *reinterpret_cast<const bf16x8*>(
              VsB + (n * 16 + lrow) * 128 + ((kvs * 64 + lg * 16) ^ sw));
          ov[0][n] = mfma16(pf0, vf, ov[0][n]);
          ov[1][n] = mfma16(pf1, vf, ov[1][n]);
        }
      }
    }

    if (!more) break;
    __syncthreads();   // everyone done reading tile t
    *reinterpret_cast<bf16x8*>(KsB + koff0) = kr0;
    *reinterpret_cast<bf16x8*>(KsB + koff1) = kr1;
    *reinterpret_cast<bf16x8*>(VsB + voff0) = vr0;
    *reinterpret_cast<bf16x8*>(VsB + voff1) = vr1;
    __syncthreads();   // tile t+1 ready
  }

  // ---- epilogue: finish row sums, normalize, store
  float rinv[2][4];
#pragma unroll
  for (int mi = 0; mi < 2; mi++)
#pragma unroll
    for (int jj = 0; jj < 4; jj++) {
      float s = ssum[mi][jj];
      s += __shfl_xor(s, 1);
      s += __shfl_xor(s, 2);
      s += __shfl_xor(s, 4);
      s += __shfl_xor(s, 8);
      rinv[mi][jj] = 1.0f / s;
    }
#pragma unroll
  for (int mi = 0; mi < 2; mi++)
#pragma unroll
    for (int n = 0; n < 8; n++)
#pragma unroll
      for (int jj = 0; jj < 4; jj++) {
        out[(size_t)(b * S_LEN + q0w + mi * 16 + lg * 4 + jj) * HIDDEN + h * HD + n * 16 + lrow] =
            (__bf16)(ov[mi][n][jj] * rinv[mi][jj]);
      }
}

// ---------------------------------------------------------------------------
// Workspace layout (bytes):
//   h_bf / a_buf (aliased) @ 0          33554432   bf16 [4096][4096]
//   Wt_big               @ 33554432     33554432   bf16 [4096][4096] (Wq^T then Wo^T)
//   Wk_t                 @ 67108864      8388608   bf16 [1024][4096]
//   Wv_t                 @ 75497472      8388608   bf16 [1024][4096]
//   q_buf                @ 83886080     33554432   bf16 [4096][4096]
//   k_buf                @ 117440512     8388608   bf16 [4096][1024]
//   v_buf                @ 125829120     8388608   bf16 [4096][1024]
//   vt_buf               @ 134217728     8388608   bf16 [16][128][2048]
// total 142606336 B
// ---------------------------------------------------------------------------
extern "C" void kernel_launch(void* const* d_in, const int* in_sizes, int n_in,
                              void* d_out, int out_size, void* d_ws, size_t ws_size,
                              hipStream_t stream) {
  const float* hidden = (const float*)d_in[0];
  const int* posids   = (const int*)d_in[1];
  const float* Wq     = (const float*)d_in[2];
  const float* Wk     = (const float*)d_in[3];
  const float* Wv     = (const float*)d_in[4];
  const float* Wo     = (const float*)d_in[5];
  float* out = (float*)d_out;

  char* ws = (char*)d_ws;
  __bf16* h_bf   = (__bf16*)(ws + 0);
  __bf16* a_buf  = h_bf;  // aliased: hidden last read before attn writes it
  __bf16* Wt_big = (__bf16*)(ws + 33554432);
  __bf16* Wk_t   = (__bf16*)(ws + 67108864);
  __bf16* Wv_t   = (__bf16*)(ws + 75497472);
  __bf16* q_buf  = (__bf16*)(ws + 83886080);
  __bf16* k_buf  = (__bf16*)(ws + 117440512);
  __bf16* v_buf  = (__bf16*)(ws + 125829120);
  __bf16* vt_buf = (__bf16*)(ws + 134217728);

  dim3 b256(256), b328(32, 8);

  // 1. hidden -> bf16
  cvt_kernel<<<dim3(MROWS * HIDDEN / (256 * 8)), b256, 0, stream>>>(hidden, h_bf, MROWS * HIDDEN);

  // 2-3. Wq^T, Q = h @ Wq
  tcvt_f32<<<dim3(HIDDEN / 32, HIDDEN / 32), b328, 0, stream>>>(Wq, Wt_big, HIDDEN, HIDDEN);
  gemm_bt<__bf16><<<dim3((HIDDEN / 128) * (MROWS / 128)), b256, 0, stream>>>(
      h_bf, Wt_big, q_buf, MROWS, HIDDEN, HIDDEN, HIDDEN / 128);

  // 4-5. Wk^T, K
  tcvt_f32<<<dim3((NKV * HD) / 32, HIDDEN / 32), b328, 0, stream>>>(Wk, Wk_t, HIDDEN, NKV * HD);
  gemm_bt<__bf16><<<dim3(((NKV * HD) / 128) * (MROWS / 128)), b256, 0, stream>>>(
      h_bf, Wk_t, k_buf, MROWS, NKV * HD, HIDDEN, (NKV * HD) / 128);

  // 6-7. Wv^T, V
  tcvt_f32<<<dim3((NKV * HD) / 32, HIDDEN / 32), b328, 0, stream>>>(Wv, Wv_t, HIDDEN, NKV * HD);
  gemm_bt<__bf16><<<dim3(((NKV * HD) / 128) * (MROWS / 128)), b256, 0, stream>>>(
      h_bf, Wv_t, v_buf, MROWS, NKV * HD, HIDDEN, (NKV * HD) / 128);

  // 8. RoPE on q,k
  rope_kernel<<<dim3(NH + NKV, MROWS), dim3(64), 0, stream>>>(q_buf, k_buf, posids);

  // 9. V^T
  tvt_kernel<<<dim3(HD / 32, S_LEN / 32, BATCH * NKV), b328, 0, stream>>>(v_buf, vt_buf);

  // 10. attention -> a_buf (overwrites h_bf region; h_bf no longer needed)
  attn_kernel<<<dim3(8 * NH * BATCH), dim3(512), 0, stream>>>(q_buf, k_buf, vt_buf, a_buf);

  // 11-12. Wo^T, out = a @ Wo (fp32 out)
  tcvt_f32<<<dim3(HIDDEN / 32, HIDDEN / 32), b328, 0, stream>>>(Wo, Wt_big, HIDDEN, HIDDEN);
  gemm_bt<float><<<dim3((HIDDEN / 128) * (MROWS / 128)), b256, 0, stream>>>(
      a_buf, Wt_big, out, MROWS, HIDDEN, HIDDEN, HIDDEN / 128);
}

// Round 4
// 590.175 us; speedup vs baseline: 4.2841x; 1.4006x over previous
//
#include <hip/hip_runtime.h>
#include <hip/hip_bf16.h>
#include <math.h>

#define HIDDEN 4096
#define NH 32
#define NKV 8
#define HD 128
#define S_LEN 2048
#define BATCH 2
#define MROWS (BATCH * S_LEN)  // 4096
#define QKVW 6144              // fused q|k|v row width

typedef __attribute__((ext_vector_type(8))) __bf16 bf16x8;
typedef __attribute__((ext_vector_type(4))) float f32x4;

__device__ __forceinline__ f32x4 mfma16(bf16x8 a, bf16x8 b, f32x4 c) {
  return __builtin_amdgcn_mfma_f32_16x16x32_bf16(a, b, c, 0, 0, 0);
}

// async global->LDS, 16B/lane; LDS dest = wave-uniform base, HW adds lane*16.
__device__ __forceinline__ void gload16(const __bf16* g, const __bf16* l) {
  __builtin_amdgcn_global_load_lds(
      (const __attribute__((address_space(1))) void*)g,
      (__attribute__((address_space(3))) void*)l, 16, 0, 0);
}

#define SBAR()                          \
  do {                                  \
    __builtin_amdgcn_sched_barrier(0);  \
    __builtin_amdgcn_s_barrier();       \
    __builtin_amdgcn_sched_barrier(0);  \
  } while (0)

// ---------------------------------------------------------------------------
// fp32 -> bf16 elementwise convert (vectorized)
// ---------------------------------------------------------------------------
__global__ __launch_bounds__(256) void cvt_kernel(const float* __restrict__ in,
                                                  __bf16* __restrict__ out, int n) {
  int i = (blockIdx.x * 256 + threadIdx.x) * 8;
  if (i >= n) return;
  float4 a = *reinterpret_cast<const float4*>(in + i);
  float4 b = *reinterpret_cast<const float4*>(in + i + 4);
  bf16x8 t;
  t[0] = (__bf16)a.x; t[1] = (__bf16)a.y; t[2] = (__bf16)a.z; t[3] = (__bf16)a.w;
  t[4] = (__bf16)b.x; t[5] = (__bf16)b.y; t[6] = (__bf16)b.z; t[7] = (__bf16)b.w;
  *reinterpret_cast<bf16x8*>(out + i) = t;
}

// ---------------------------------------------------------------------------
// Transpose + convert: out[c][r] = (bf16) in[r][c].  in: [R][C] fp32.
// block (32,8), grid (C/32, R/32).
// ---------------------------------------------------------------------------
__global__ __launch_bounds__(256) void tcvt_f32(const float* __restrict__ in,
                                                __bf16* __restrict__ out,
                                                int R, int C) {
  __shared__ float t[32][33];
  int tx = threadIdx.x, ty = threadIdx.y;
  int r0 = blockIdx.y * 32, c0 = blockIdx.x * 32;
#pragma unroll
  for (int i = 0; i < 4; i++)
    t[ty + i * 8][tx] = in[(size_t)(r0 + ty + i * 8) * C + c0 + tx];
  __syncthreads();
#pragma unroll
  for (int i = 0; i < 4; i++)
    out[(size_t)(c0 + ty + i * 8) * R + r0 + tx] = (__bf16)t[tx][ty + i * 8];
}

// ---------------------------------------------------------------------------
// V transpose: qkv [B*S][QKVW] (v at col 5120 + kvh*HD) -> vt [B*NKV][HD][S].
// grid (HD/32, S/32, B*NKV), block (32,8).
// ---------------------------------------------------------------------------
__global__ __launch_bounds__(256) void tvt_kernel(const __bf16* __restrict__ qkv,
                                                  __bf16* __restrict__ vt) {
  __shared__ __bf16 t[32][33];
  int tx = threadIdx.x, ty = threadIdx.y;
  int z = blockIdx.z;
  int b = z >> 3, kvh = z & 7;
  int kv0 = blockIdx.y * 32, d0 = blockIdx.x * 32;
#pragma unroll
  for (int i = 0; i < 4; i++)
    t[ty + i * 8][tx] =
        qkv[(size_t)(b * S_LEN + kv0 + ty + i * 8) * QKVW + 5120 + kvh * HD + d0 + tx];
  __syncthreads();
#pragma unroll
  for (int i = 0; i < 4; i++)
    vt[((size_t)z * HD + d0 + ty + i * 8) * S_LEN + kv0 + tx] = t[tx][ty + i * 8];
}

// ---------------------------------------------------------------------------
// 256x256 8-phase GEMM (m201-style): C[M,N] = A[M,K] * Bt[N,K]^T.
// 512 threads = 8 waves (2M x 4N); BK=64; LDS 128KB = 2(dbuf) x (A 32KB + B
// 32KB). Wave w: rows (w>>2)*64 + (i&3)*16 + (i>>2)*128, cols (w&3)*32 +
// (j&1)*16 + (j>>1)*128  (i<8 m-frags, j<4 n-frags, per-wave 128x64 out).
// LDS swizzle: byte ^= (row&7)<<4, realized as linear gload_lds dest +
// inverse-swizzled per-lane GLOBAL source + swizzled ds_read (rule #21).
// Phases per K-tile T (parity p=T&1):
//   ph0 (Ah0,Bh0) stage A(T+1)h1   ph1 (Ah0,Bh1) stage B(T+1)h1
//   ph2 (Ah1,Bh0) stage A(T+2)h0   ph3 (Ah1,Bh1) stage B(T+2)h0
// Region deaths: A-p-h0 after ph0 reads, B-p-h0 after ph0, A-p-h1 after ph2,
// B-p-h1 after ph1 -> every stage targets a dead (or other-parity) region.
// vmcnt(4) ONLY at tile boundary (tile T+1 = 8 oldest loads drained; 4 in
// flight = tile T+2 h0 pair). Tail stages clamp source to tile 0 (garbage
// into dead regions, keeps vmcnt counts uniform).
// ---------------------------------------------------------------------------
template<typename CT>
__global__ __launch_bounds__(512, 2) void gemm256(const __bf16* __restrict__ A,
                                                  const __bf16* __restrict__ Bt,
                                                  CT* __restrict__ C,
                                                  int M, int N, int K, int nbx) {
  __shared__ char lds[131072];
  const int tid = threadIdx.x;
  const int l = tid & 63, w = tid >> 6;
  const int lrow = l & 15, lg = l >> 4;
  const int sw = (lrow & 7) << 4;

  int nwg = gridDim.x;
  int swz = (blockIdx.x & 7) * (nwg >> 3) + (blockIdx.x >> 3);
  int bx = swz % nbx, by = swz / nbx;
  int m0 = by * 256, n0 = bx * 256;

  // staging: thread covers dest rows w*8 + (l>>3) + p*64 within a half-tile,
  // source col pre-swizzled so linear LDS + swizzled read is consistent.
  const int rA = w * 8 + (l >> 3);
  const int csw = ((l & 7) ^ (l >> 3)) * 8;  // element col in source row
  const __bf16* As_[2][2];
  const __bf16* Bs_[2][2];
#pragma unroll
  for (int h = 0; h < 2; h++)
#pragma unroll
    for (int p = 0; p < 2; p++) {
      As_[h][p] = A + (size_t)(m0 + h * 128 + p * 64 + rA) * K + csw;
      Bs_[h][p] = Bt + (size_t)(n0 + h * 128 + p * 64 + rA) * K + csw;
    }

  auto stageA = [&](int par, int h, int kt) {
#pragma unroll
    for (int p = 0; p < 2; p++)
      gload16(As_[h][p] + kt * 64,
              (const __bf16*)(lds + par * 32768 + h * 16384 + p * 8192 + w * 1024));
  };
  auto stageB = [&](int par, int h, int kt) {
#pragma unroll
    for (int p = 0; p < 2; p++)
      gload16(Bs_[h][p] + kt * 64,
              (const __bf16*)(lds + 65536 + par * 32768 + h * 16384 + p * 8192 + w * 1024));
  };

  const int arbase = (w >> 2) * 64 + lrow;
  const int brbase = (w & 3) * 32 + lrow;

  bf16x8 aA[4][2];        // current A-half frags
  bf16x8 bB[2][2][2];     // both B-half frags, held across the tile

  auto readA = [&](int par, int ah) {
#pragma unroll
    for (int i = 0; i < 4; i++)
#pragma unroll
      for (int kk = 0; kk < 2; kk++)
        aA[i][kk] = *reinterpret_cast<const bf16x8*>(
            lds + par * 32768 + (arbase + i * 16 + ah * 128) * 128 +
            ((kk * 64 + lg * 16) ^ sw));
  };
  auto readB = [&](int par, int bh) {
#pragma unroll
    for (int j = 0; j < 2; j++)
#pragma unroll
      for (int kk = 0; kk < 2; kk++)
        bB[bh][j][kk] = *reinterpret_cast<const bf16x8*>(
            lds + 65536 + par * 32768 + (brbase + j * 16 + bh * 128) * 128 +
            ((kk * 64 + lg * 16) ^ sw));
  };

  f32x4 acc[8][4];
#pragma unroll
  for (int i = 0; i < 8; i++)
#pragma unroll
    for (int j = 0; j < 4; j++) {
      acc[i][j][0] = 0.f; acc[i][j][1] = 0.f; acc[i][j][2] = 0.f; acc[i][j][3] = 0.f;
    }

  const int NT = K >> 6;

  // prologue: tile0 (all 4 halves) + tile1 h0 pair; wait tile0 (4 in flight)
  stageA(0, 0, 0); stageA(0, 1, 0); stageB(0, 0, 0); stageB(0, 1, 0);
  stageA(1, 0, 1); stageB(1, 0, 1);
  __builtin_amdgcn_sched_barrier(0);
  asm volatile("s_waitcnt vmcnt(4)" ::: "memory");
  SBAR();

  for (int t = 0; t < NT; t++) {
    const int par = t & 1, npar = par ^ 1;
    const int t1 = (t + 1 < NT) ? t + 1 : 0;
    const int t2 = (t + 2 < NT) ? t + 2 : 0;

#define MFMA_QUAD(AH, BH)                                                   \
  __builtin_amdgcn_s_setprio(1);                                            \
  _Pragma("unroll") for (int i4 = 0; i4 < 4; i4++)                          \
      _Pragma("unroll") for (int j2 = 0; j2 < 2; j2++)                      \
          _Pragma("unroll") for (int kk = 0; kk < 2; kk++)                  \
              acc[(AH)*4 + i4][(BH)*2 + j2] =                               \
                  mfma16(aA[i4][kk], bB[BH][j2][kk], acc[(AH)*4 + i4][(BH)*2 + j2]); \
  __builtin_amdgcn_s_setprio(0);

    // ph0: (A h0, B h0); stage A(t+1)h1
    readA(par, 0);
    readB(par, 0);
    stageA(npar, 1, t1);
    SBAR();
    MFMA_QUAD(0, 0);
    SBAR();
    // ph1: (A h0, B h1); stage B(t+1)h1
    readB(par, 1);
    stageB(npar, 1, t1);
    SBAR();
    MFMA_QUAD(0, 1);
    SBAR();
    // ph2: (A h1, B h0); stage A(t+2)h0
    readA(par, 1);
    stageA(par, 0, t2);
    SBAR();
    MFMA_QUAD(1, 0);
    SBAR();
    // ph3: (A h1, B h1); stage B(t+2)h0
    stageB(par, 0, t2);
    SBAR();
    MFMA_QUAD(1, 1);
    // tile boundary: counted vmcnt, never 0
    __builtin_amdgcn_sched_barrier(0);
    asm volatile("s_waitcnt vmcnt(4)" ::: "memory");
    SBAR();
#undef MFMA_QUAD
  }

#pragma unroll
  for (int i = 0; i < 8; i++) {
    int row = m0 + (w >> 2) * 64 + (i & 3) * 16 + (i >> 2) * 128 + lg * 4;
#pragma unroll
    for (int j = 0; j < 4; j++) {
      int col = n0 + (w & 3) * 32 + (j & 1) * 16 + (j >> 1) * 128 + lrow;
#pragma unroll
      for (int jj = 0; jj < 4; jj++)
        C[(size_t)(row + jj) * N + col] = (CT)acc[i][j][jj];
    }
  }
}

// ---------------------------------------------------------------------------
// RoPE, in-place on fused qkv buffer. grid (NH+NKV, B*S), block 64.
// ---------------------------------------------------------------------------
__global__ __launch_bounds__(64) void rope_kernel(__bf16* __restrict__ qkv,
                                                  const int* __restrict__ pos) {
  int pair = threadIdx.x;   // 0..63
  int head = blockIdx.x;
  int row = blockIdx.y;
  int p = pos[row];
  float inv = exp2f(-0.20762050f * (float)pair);   // 10000^(-pair/64)
  float ang = (float)p * inv;
  float s, c;
  __sincosf(ang, &s, &c);
  __bf16* base = qkv + (size_t)row * QKVW +
                 (head < NH ? head * HD : 4096 + (head - NH) * HD);
  float x1 = (float)base[pair];
  float x2 = (float)base[pair + 64];
  base[pair]      = (__bf16)(x1 * c - x2 * s);
  base[pair + 64] = (__bf16)(x2 * c + x1 * s);
}

// ---------------------------------------------------------------------------
// Flash attention, causal, GQA. 8-wave blocks, wave w owns 32 q rows of a
// 256-row q block; KVBLK=64; K/V^T reg-staged to XOR-swizzled LDS; T14 split.
// Reads fused qkv buffer (q at col 0, k at col 4096), V^T from vt.
// ---------------------------------------------------------------------------
__global__ __launch_bounds__(512) void attn_kernel(const __bf16* __restrict__ qkv,
                                                   const __bf16* __restrict__ vt,
                                                   __bf16* __restrict__ out) {
  __shared__ __bf16 Ks[64 * 128];      // [kv][d], swizzled, 16 KB
  __shared__ __bf16 Vs[128 * 64];      // [d][kv], swizzled, 16 KB
  __shared__ __bf16 Ps[8][32][68];     // per-wave P, padded, 34 KB

  int tid = threadIdx.x;
  int l = tid & 63, w = tid >> 6;
  int bid = blockIdx.x;
  int qblk = 7 - (bid >> 6);           // heavy blocks first
  int rem = bid & 63;
  int h = rem & 31, b = rem >> 5;
  int kvh = h >> 2;
  int q0w = qblk * 256 + w * 32;
  int lrow = l & 15, lg = l >> 4;
  int sw = (lrow & 7) << 4;
  const float SCL = 0.08838834764831845f * 1.4426950408889634f;  // 1/sqrt(128)*log2e

  const __bf16* kbase = qkv + (size_t)(b * S_LEN) * QKVW + 4096 + kvh * HD;
  const __bf16* vbase = vt + ((size_t)(b * NKV + kvh) * HD) * S_LEN;

  int krow = tid >> 3;                 // 0..63
  int kslot = (tid & 7) * 2;           // 0..14
  int vrow = tid >> 2;                 // 0..127
  int vslot = (tid & 3) * 2;           // 0..6
  char* KsB = (char*)Ks;
  char* VsB = (char*)Vs;
  int koff0 = krow * 256 + ((kslot * 16) ^ ((krow & 7) << 4));
  int koff1 = krow * 256 + (((kslot + 1) * 16) ^ ((krow & 7) << 4));
  int voff0 = vrow * 128 + ((vslot * 16) ^ ((vrow & 7) << 4));
  int voff1 = vrow * 128 + (((vslot + 1) * 16) ^ ((vrow & 7) << 4));
  const __bf16* kg = kbase + (size_t)krow * QKVW + kslot * 8;
  const __bf16* vg = vbase + (size_t)vrow * S_LEN + vslot * 8;

  // Q fragments, pre-scaled
  bf16x8 qf[2][4];
#pragma unroll
  for (int mi = 0; mi < 2; mi++) {
    const __bf16* qp = qkv + (size_t)(b * S_LEN + q0w + mi * 16 + lrow) * QKVW + h * HD + lg * 8;
#pragma unroll
    for (int kk = 0; kk < 4; kk++) {
      bf16x8 t = *reinterpret_cast<const bf16x8*>(qp + kk * 32);
#pragma unroll
      for (int e = 0; e < 8; e++) t[e] = (__bf16)((float)t[e] * SCL);
      qf[mi][kk] = t;
    }
  }

  f32x4 ov[2][8];
#pragma unroll
  for (int mi = 0; mi < 2; mi++)
#pragma unroll
    for (int n = 0; n < 8; n++) {
      ov[mi][n][0] = 0.f; ov[mi][n][1] = 0.f; ov[mi][n][2] = 0.f; ov[mi][n][3] = 0.f;
    }
  float m[2][4], ssum[2][4];
#pragma unroll
  for (int mi = 0; mi < 2; mi++)
#pragma unroll
    for (int jj = 0; jj < 4; jj++) { m[mi][jj] = -3.0e38f; ssum[mi][jj] = 0.f; }

  int nt = 4 * qblk + 4;
  bf16x8 kr0, kr1, vr0, vr1;

  // prologue: stage tile 0
  kr0 = *reinterpret_cast<const bf16x8*>(kg);
  kr1 = *reinterpret_cast<const bf16x8*>(kg + 8);
  vr0 = *reinterpret_cast<const bf16x8*>(vg);
  vr1 = *reinterpret_cast<const bf16x8*>(vg + 8);
  *reinterpret_cast<bf16x8*>(KsB + koff0) = kr0;
  *reinterpret_cast<bf16x8*>(KsB + koff1) = kr1;
  *reinterpret_cast<bf16x8*>(VsB + voff0) = vr0;
  *reinterpret_cast<bf16x8*>(VsB + voff1) = vr1;
  __syncthreads();

  for (int t = 0;; t++) {
    int kv0 = t * 64;
    bool more = (t + 1 < nt);
    if (more) {
      int kvn = kv0 + 64;
      kr0 = *reinterpret_cast<const bf16x8*>(kg + (size_t)kvn * QKVW);
      kr1 = *reinterpret_cast<const bf16x8*>(kg + (size_t)kvn * QKVW + 8);
      vr0 = *reinterpret_cast<const bf16x8*>(vg + kvn);
      vr1 = *reinterpret_cast<const bf16x8*>(vg + kvn + 8);
    }

    bool active = (kv0 <= q0w + 31);
    if (active) {
      // ---- QK^T from swizzled LDS: 32 q rows x 64 kv cols
      f32x4 sc[2][4];
#pragma unroll
      for (int mi = 0; mi < 2; mi++)
#pragma unroll
        for (int c = 0; c < 4; c++) {
          sc[mi][c][0] = 0.f; sc[mi][c][1] = 0.f; sc[mi][c][2] = 0.f; sc[mi][c][3] = 0.f;
        }
#pragma unroll
      for (int c = 0; c < 4; c++) {
        int rb = (c * 16 + lrow) * 256;
#pragma unroll
        for (int kk = 0; kk < 4; kk++) {
          bf16x8 kf = *reinterpret_cast<const bf16x8*>(KsB + rb + ((kk * 64 + lg * 16) ^ sw));
          sc[0][c] = mfma16(qf[0][kk], kf, sc[0][c]);
          sc[1][c] = mfma16(qf[1][kk], kf, sc[1][c]);
        }
      }

      // ---- online softmax (exp2 domain)
      bool bound = (kv0 + 64 > q0w);
      float es[2][4];
      bool anyr = false;
#pragma unroll
      for (int mi = 0; mi < 2; mi++)
#pragma unroll
        for (int jj = 0; jj < 4; jj++) {
          int qidx = q0w + mi * 16 + lg * 4 + jj;
          float s0 = sc[mi][0][jj], s1 = sc[mi][1][jj];
          float s2 = sc[mi][2][jj], s3 = sc[mi][3][jj];
          if (bound) {
            if (kv0 + lrow > qidx)      s0 = -3.0e38f;
            if (kv0 + 16 + lrow > qidx) s1 = -3.0e38f;
            if (kv0 + 32 + lrow > qidx) s2 = -3.0e38f;
            if (kv0 + 48 + lrow > qidx) s3 = -3.0e38f;
          }
          float r = fmaxf(fmaxf(s0, s1), fmaxf(s2, s3));
          r = fmaxf(r, __shfl_xor(r, 1));
          r = fmaxf(r, __shfl_xor(r, 2));
          r = fmaxf(r, __shfl_xor(r, 4));
          r = fmaxf(r, __shfl_xor(r, 8));
          float mo = m[mi][jj];
          float mn = fmaxf(mo, r);
          float e = exp2f(mo - mn);
          es[mi][jj] = e;
          anyr |= (mn > mo);
          m[mi][jj] = mn;
          float p0 = exp2f(s0 - mn), p1 = exp2f(s1 - mn);
          float p2 = exp2f(s2 - mn), p3 = exp2f(s3 - mn);
          ssum[mi][jj] = ssum[mi][jj] * e + ((p0 + p1) + (p2 + p3));
          int pr = mi * 16 + lg * 4 + jj;
          Ps[w][pr][lrow]      = (__bf16)p0;
          Ps[w][pr][16 + lrow] = (__bf16)p1;
          Ps[w][pr][32 + lrow] = (__bf16)p2;
          Ps[w][pr][48 + lrow] = (__bf16)p3;
        }
      if (__any(anyr)) {
#pragma unroll
        for (int mi = 0; mi < 2; mi++)
#pragma unroll
          for (int n = 0; n < 8; n++)
#pragma unroll
            for (int jj = 0; jj < 4; jj++) ov[mi][n][jj] *= es[mi][jj];
      }

      // ---- PV from swizzled LDS
#pragma unroll
      for (int kvs = 0; kvs < 2; kvs++) {
        bf16x8 pf0 = *reinterpret_cast<const bf16x8*>(&Ps[w][lrow][kvs * 32 + lg * 8]);
        bf16x8 pf1 = *reinterpret_cast<const bf16x8*>(&Ps[w][16 + lrow][kvs * 32 + lg * 8]);
#pragma unroll
        for (int n = 0; n < 8; n++) {
          bf16x8 vf = *reinterpret_cast<const bf16x8*>(
              VsB + (n * 16 + lrow) * 128 + ((kvs * 64 + lg * 16) ^ sw));
          ov[0][n] = mfma16(pf0, vf, ov[0][n]);
          ov[1][n] = mfma16(pf1, vf, ov[1][n]);
        }
      }
    }

    if (!more) break;
    __syncthreads();
    *reinterpret_cast<bf16x8*>(KsB + koff0) = kr0;
    *reinterpret_cast<bf16x8*>(KsB + koff1) = kr1;
    *reinterpret_cast<bf16x8*>(VsB + voff0) = vr0;
    *reinterpret_cast<bf16x8*>(VsB + voff1) = vr1;
    __syncthreads();
  }

  float rinv[2][4];
#pragma unroll
  for (int mi = 0; mi < 2; mi++)
#pragma unroll
    for (int jj = 0; jj < 4; jj++) {
      float s = ssum[mi][jj];
      s += __shfl_xor(s, 1);
      s += __shfl_xor(s, 2);
      s += __shfl_xor(s, 4);
      s += __shfl_xor(s, 8);
      rinv[mi][jj] = 1.0f / s;
    }
#pragma unroll
  for (int mi = 0; mi < 2; mi++)
#pragma unroll
    for (int n = 0; n < 8; n++)
#pragma unroll
      for (int jj = 0; jj < 4; jj++) {
        out[(size_t)(b * S_LEN + q0w + mi * 16 + lg * 4 + jj) * HIDDEN + h * HD + n * 16 + lrow] =
            (__bf16)(ov[mi][n][jj] * rinv[mi][jj]);
      }
}

// ---------------------------------------------------------------------------
// Workspace layout (bytes), total 142606336 (same footprint as round 2/3):
//   h_bf / a_buf (aliased) @ 0          33554432   bf16 [4096][4096]
//   Wt (qkv^T, later Wo^T) @ 33554432   50331648   bf16 [6144][4096]
//   qkv_buf                @ 83886080   50331648   bf16 [4096][6144]
//   vt_buf                 @ 134217728   8388608   bf16 [16][128][2048]
// ---------------------------------------------------------------------------
extern "C" void kernel_launch(void* const* d_in, const int* in_sizes, int n_in,
                              void* d_out, int out_size, void* d_ws, size_t ws_size,
                              hipStream_t stream) {
  const float* hidden = (const float*)d_in[0];
  const int* posids   = (const int*)d_in[1];
  const float* Wq     = (const float*)d_in[2];
  const float* Wk     = (const float*)d_in[3];
  const float* Wv     = (const float*)d_in[4];
  const float* Wo     = (const float*)d_in[5];
  float* out = (float*)d_out;

  char* ws = (char*)d_ws;
  __bf16* h_bf    = (__bf16*)(ws + 0);
  __bf16* a_buf   = h_bf;  // aliased: h last read by QKV GEMM, before attn writes
  __bf16* Wt      = (__bf16*)(ws + 33554432);
  __bf16* qkv_buf = (__bf16*)(ws + 83886080);
  __bf16* vt_buf  = (__bf16*)(ws + 134217728);

  dim3 b256(256), b328(32, 8), b512(512);

  // 1. hidden -> bf16
  cvt_kernel<<<dim3(MROWS * HIDDEN / (256 * 8)), b256, 0, stream>>>(hidden, h_bf, MROWS * HIDDEN);

  // 2. fused weight transpose: Wt = [Wq^T ; Wk^T ; Wv^T]  [6144][4096]
  tcvt_f32<<<dim3(HIDDEN / 32, HIDDEN / 32), b328, 0, stream>>>(Wq, Wt, HIDDEN, HIDDEN);
  tcvt_f32<<<dim3((NKV * HD) / 32, HIDDEN / 32), b328, 0, stream>>>(
      Wk, Wt + (size_t)4096 * 4096, HIDDEN, NKV * HD);
  tcvt_f32<<<dim3((NKV * HD) / 32, HIDDEN / 32), b328, 0, stream>>>(
      Wv, Wt + (size_t)5120 * 4096, HIDDEN, NKV * HD);

  // 3. fused QKV GEMM: qkv = h @ [Wq|Wk|Wv]   (M=4096, N=6144, K=4096)
  gemm256<__bf16><<<dim3((QKVW / 256) * (MROWS / 256)), b512, 0, stream>>>(
      h_bf, Wt, qkv_buf, MROWS, QKVW, HIDDEN, QKVW / 256);

  // 4. RoPE on q,k (in fused buffer)
  rope_kernel<<<dim3(NH + NKV, MROWS), dim3(64), 0, stream>>>(qkv_buf, posids);

  // 5. V^T
  tvt_kernel<<<dim3(HD / 32, S_LEN / 32, BATCH * NKV), b328, 0, stream>>>(qkv_buf, vt_buf);

  // 6. attention -> a_buf
  attn_kernel<<<dim3(8 * NH * BATCH), b512, 0, stream>>>(qkv_buf, vt_buf, a_buf);

  // 7. Wo^T (reuse Wt)
  tcvt_f32<<<dim3(HIDDEN / 32, HIDDEN / 32), b328, 0, stream>>>(Wo, Wt, HIDDEN, HIDDEN);

  // 8. out = a @ Wo  (fp32 out; M=N=K=4096)
  gemm256<float><<<dim3((HIDDEN / 256) * (MROWS / 256)), b512, 0, stream>>>(
      a_buf, Wt, out, MROWS, HIDDEN, HIDDEN, HIDDEN / 256);
}

// Round 5
// 555.755 us; speedup vs baseline: 4.5494x; 1.0619x over previous
//
#include <hip/hip_runtime.h>
#include <hip/hip_bf16.h>
#include <math.h>

#define HIDDEN 4096
#define NH 32
#define NKV 8
#define HD 128
#define S_LEN 2048
#define BATCH 2
#define MROWS (BATCH * S_LEN)  // 4096
#define QKVW 6144              // fused q|k|v row width

typedef __attribute__((ext_vector_type(8))) __bf16 bf16x8;
typedef __attribute__((ext_vector_type(4))) float f32x4;

__device__ __forceinline__ f32x4 mfma16(bf16x8 a, bf16x8 b, f32x4 c) {
  return __builtin_amdgcn_mfma_f32_16x16x32_bf16(a, b, c, 0, 0, 0);
}

// async global->LDS, 16B/lane; LDS dest = wave-uniform base, HW adds lane*16.
__device__ __forceinline__ void gload16(const __bf16* g, const __bf16* l) {
  __builtin_amdgcn_global_load_lds(
      (const __attribute__((address_space(1))) void*)g,
      (__attribute__((address_space(3))) void*)l, 16, 0, 0);
}

#define SBAR()                          \
  do {                                  \
    __builtin_amdgcn_sched_barrier(0);  \
    __builtin_amdgcn_s_barrier();       \
    __builtin_amdgcn_sched_barrier(0);  \
  } while (0)

// ---------------------------------------------------------------------------
// fp32 -> bf16 elementwise convert (vectorized)
// ---------------------------------------------------------------------------
__global__ __launch_bounds__(256) void cvt_kernel(const float* __restrict__ in,
                                                  __bf16* __restrict__ out, int n) {
  int i = (blockIdx.x * 256 + threadIdx.x) * 8;
  if (i >= n) return;
  float4 a = *reinterpret_cast<const float4*>(in + i);
  float4 b = *reinterpret_cast<const float4*>(in + i + 4);
  bf16x8 t;
  t[0] = (__bf16)a.x; t[1] = (__bf16)a.y; t[2] = (__bf16)a.z; t[3] = (__bf16)a.w;
  t[4] = (__bf16)b.x; t[5] = (__bf16)b.y; t[6] = (__bf16)b.z; t[7] = (__bf16)b.w;
  *reinterpret_cast<bf16x8*>(out + i) = t;
}

// ---------------------------------------------------------------------------
// Transpose + convert: out[c][r] = (bf16) in[r][c].  in: [R][C] fp32.
// block (32,8), grid (C/32, R/32).
// ---------------------------------------------------------------------------
__global__ __launch_bounds__(256) void tcvt_f32(const float* __restrict__ in,
                                                __bf16* __restrict__ out,
                                                int R, int C) {
  __shared__ float t[32][33];
  int tx = threadIdx.x, ty = threadIdx.y;
  int r0 = blockIdx.y * 32, c0 = blockIdx.x * 32;
#pragma unroll
  for (int i = 0; i < 4; i++)
    t[ty + i * 8][tx] = in[(size_t)(r0 + ty + i * 8) * C + c0 + tx];
  __syncthreads();
#pragma unroll
  for (int i = 0; i < 4; i++)
    out[(size_t)(c0 + ty + i * 8) * R + r0 + tx] = (__bf16)t[tx][ty + i * 8];
}

// ---------------------------------------------------------------------------
// V transpose: qkv [B*S][QKVW] (v at col 5120 + kvh*HD) -> vt [B*NKV][HD][S].
// grid (HD/32, S/32, B*NKV), block (32,8).
// ---------------------------------------------------------------------------
__global__ __launch_bounds__(256) void tvt_kernel(const __bf16* __restrict__ qkv,
                                                  __bf16* __restrict__ vt) {
  __shared__ __bf16 t[32][33];
  int tx = threadIdx.x, ty = threadIdx.y;
  int z = blockIdx.z;
  int b = z >> 3, kvh = z & 7;
  int kv0 = blockIdx.y * 32, d0 = blockIdx.x * 32;
#pragma unroll
  for (int i = 0; i < 4; i++)
    t[ty + i * 8][tx] =
        qkv[(size_t)(b * S_LEN + kv0 + ty + i * 8) * QKVW + 5120 + kvh * HD + d0 + tx];
  __syncthreads();
#pragma unroll
  for (int i = 0; i < 4; i++)
    vt[((size_t)z * HD + d0 + ty + i * 8) * S_LEN + kv0 + tx] = t[tx][ty + i * 8];
}

// ---------------------------------------------------------------------------
// 256x256 8-phase GEMM (m201-style): C[M,N] = A[M,K] * Bt[N,K]^T.
// (used for Wo: 256 blocks = 1 balanced round)
// ---------------------------------------------------------------------------
template<typename CT>
__global__ __launch_bounds__(512, 2) void gemm256(const __bf16* __restrict__ A,
                                                  const __bf16* __restrict__ Bt,
                                                  CT* __restrict__ C,
                                                  int M, int N, int K, int nbx) {
  __shared__ char lds[131072];
  const int tid = threadIdx.x;
  const int l = tid & 63, w = tid >> 6;
  const int lrow = l & 15, lg = l >> 4;
  const int sw = (lrow & 7) << 4;

  int nwg = gridDim.x;
  int swz = (blockIdx.x & 7) * (nwg >> 3) + (blockIdx.x >> 3);
  int bx = swz % nbx, by = swz / nbx;
  int m0 = by * 256, n0 = bx * 256;

  const int rA = w * 8 + (l >> 3);
  const int csw = ((l & 7) ^ (l >> 3)) * 8;  // inverse-swizzled source col
  const __bf16* As_[2][2];
  const __bf16* Bs_[2][2];
#pragma unroll
  for (int h = 0; h < 2; h++)
#pragma unroll
    for (int p = 0; p < 2; p++) {
      As_[h][p] = A + (size_t)(m0 + h * 128 + p * 64 + rA) * K + csw;
      Bs_[h][p] = Bt + (size_t)(n0 + h * 128 + p * 64 + rA) * K + csw;
    }

  auto stageA = [&](int par, int h, int kt) {
#pragma unroll
    for (int p = 0; p < 2; p++)
      gload16(As_[h][p] + kt * 64,
              (const __bf16*)(lds + par * 32768 + h * 16384 + p * 8192 + w * 1024));
  };
  auto stageB = [&](int par, int h, int kt) {
#pragma unroll
    for (int p = 0; p < 2; p++)
      gload16(Bs_[h][p] + kt * 64,
              (const __bf16*)(lds + 65536 + par * 32768 + h * 16384 + p * 8192 + w * 1024));
  };

  const int arbase = (w >> 2) * 64 + lrow;
  const int brbase = (w & 3) * 32 + lrow;

  bf16x8 aA[4][2];
  bf16x8 bB[2][2][2];

  auto readA = [&](int par, int ah) {
#pragma unroll
    for (int i = 0; i < 4; i++)
#pragma unroll
      for (int kk = 0; kk < 2; kk++)
        aA[i][kk] = *reinterpret_cast<const bf16x8*>(
            lds + par * 32768 + (arbase + i * 16 + ah * 128) * 128 +
            ((kk * 64 + lg * 16) ^ sw));
  };
  auto readB = [&](int par, int bh) {
#pragma unroll
    for (int j = 0; j < 2; j++)
#pragma unroll
      for (int kk = 0; kk < 2; kk++)
        bB[bh][j][kk] = *reinterpret_cast<const bf16x8*>(
            lds + 65536 + par * 32768 + (brbase + j * 16 + bh * 128) * 128 +
            ((kk * 64 + lg * 16) ^ sw));
  };

  f32x4 acc[8][4];
#pragma unroll
  for (int i = 0; i < 8; i++)
#pragma unroll
    for (int j = 0; j < 4; j++) {
      acc[i][j][0] = 0.f; acc[i][j][1] = 0.f; acc[i][j][2] = 0.f; acc[i][j][3] = 0.f;
    }

  const int NT = K >> 6;

  stageA(0, 0, 0); stageA(0, 1, 0); stageB(0, 0, 0); stageB(0, 1, 0);
  stageA(1, 0, 1); stageB(1, 0, 1);
  __builtin_amdgcn_sched_barrier(0);
  asm volatile("s_waitcnt vmcnt(4)" ::: "memory");
  SBAR();

  for (int t = 0; t < NT; t++) {
    const int par = t & 1, npar = par ^ 1;
    const int t1 = (t + 1 < NT) ? t + 1 : 0;
    const int t2 = (t + 2 < NT) ? t + 2 : 0;

#define MFMA_QUAD(AH, BH)                                                   \
  __builtin_amdgcn_s_setprio(1);                                            \
  _Pragma("unroll") for (int i4 = 0; i4 < 4; i4++)                          \
      _Pragma("unroll") for (int j2 = 0; j2 < 2; j2++)                      \
          _Pragma("unroll") for (int kk = 0; kk < 2; kk++)                  \
              acc[(AH)*4 + i4][(BH)*2 + j2] =                               \
                  mfma16(aA[i4][kk], bB[BH][j2][kk], acc[(AH)*4 + i4][(BH)*2 + j2]); \
  __builtin_amdgcn_s_setprio(0);

    readA(par, 0);
    readB(par, 0);
    stageA(npar, 1, t1);
    SBAR();
    MFMA_QUAD(0, 0);
    SBAR();
    readB(par, 1);
    stageB(npar, 1, t1);
    SBAR();
    MFMA_QUAD(0, 1);
    SBAR();
    readA(par, 1);
    stageA(par, 0, t2);
    SBAR();
    MFMA_QUAD(1, 0);
    SBAR();
    stageB(par, 0, t2);
    SBAR();
    MFMA_QUAD(1, 1);
    __builtin_amdgcn_sched_barrier(0);
    asm volatile("s_waitcnt vmcnt(4)" ::: "memory");
    SBAR();
#undef MFMA_QUAD
  }

#pragma unroll
  for (int i = 0; i < 8; i++) {
    int row = m0 + (w >> 2) * 64 + (i & 3) * 16 + (i >> 2) * 128 + lg * 4;
#pragma unroll
    for (int j = 0; j < 4; j++) {
      int col = n0 + (w & 3) * 32 + (j & 1) * 16 + (j >> 1) * 128 + lrow;
#pragma unroll
      for (int jj = 0; jj < 4; jj++)
        C[(size_t)(row + jj) * N + col] = (CT)acc[i][j][jj];
    }
  }
}

// ---------------------------------------------------------------------------
// 256x128 8-phase-family GEMM: C[M,N] = A[M,K] * Bt[N,K]^T, 2 phases/K-tile,
// 16 MFMA each. Grid = (M/256)*(N/128) — chosen so QKV (16x48=768) and any
// N%128==0 shape gives full 256-block rounds. 512 threads = 8 waves, per-wave
// out 128x32 (i<8 m-frags over two 128-row A-halves, j<2 n-frags). LDS 96KB:
// A dbuf 2x32KB (same layout as gemm256), B dbuf 2x16KB (128 rows x 128B).
// Phase/staging schedule per tile t (par=t&1):
//   ph0: readA(par,h0)+readB(par); stage Ah1(t+1,npar)+B(t+1,npar); bar; 16 MFMA; bar
//   ph1: readA(par,h1);            stage Ah0(t+2,par);              bar; 16 MFMA;
//        vmcnt(2); bar
// Region deaths: A-par-h0 dead after ph0 reads (stage Ah0(t+2) at ph1 safe);
// npar regions safe (last read 1 tile ago, barriers crossed). In-flight at
// boundary: Ah0(t+1)[from t-1] + Ah1(t+1) + B(t+1) + Ah0(t+2) = 8; drain 6
// oldest (= tile t+1 complete) -> vmcnt(2), never 0.
// ---------------------------------------------------------------------------
template<typename CT>
__global__ __launch_bounds__(512, 2) void gemm128(const __bf16* __restrict__ A,
                                                  const __bf16* __restrict__ Bt,
                                                  CT* __restrict__ C,
                                                  int M, int N, int K, int nbx) {
  __shared__ char lds[98304];
  const int tid = threadIdx.x;
  const int l = tid & 63, w = tid >> 6;
  const int lrow = l & 15, lg = l >> 4;
  const int sw = (lrow & 7) << 4;

  int nwg = gridDim.x;
  int swz = (blockIdx.x & 7) * (nwg >> 3) + (blockIdx.x >> 3);
  int bx = swz % nbx, by = swz / nbx;
  int m0 = by * 256, n0 = bx * 128;

  const int rA = w * 8 + (l >> 3);           // 0..63 within a 64-row stripe
  const int csw = ((l & 7) ^ (l >> 3)) * 8;  // inverse-swizzled source col
  const __bf16* As_[2][2];
  const __bf16* Bs_[2];
#pragma unroll
  for (int h = 0; h < 2; h++)
#pragma unroll
    for (int p = 0; p < 2; p++)
      As_[h][p] = A + (size_t)(m0 + h * 128 + p * 64 + rA) * K + csw;
#pragma unroll
  for (int p = 0; p < 2; p++)
    Bs_[p] = Bt + (size_t)(n0 + p * 64 + rA) * K + csw;

  // A: lds[0,65536): par*32768 + h*16384 + p*8192 + w*1024 (row stride 128B)
  auto stageA = [&](int par, int h, int kt) {
#pragma unroll
    for (int p = 0; p < 2; p++)
      gload16(As_[h][p] + kt * 64,
              (const __bf16*)(lds + par * 32768 + h * 16384 + p * 8192 + w * 1024));
  };
  // B: lds[65536,98304): par*16384 + p*8192 + w*1024
  auto stageB = [&](int par, int kt) {
#pragma unroll
    for (int p = 0; p < 2; p++)
      gload16(Bs_[p] + kt * 64,
              (const __bf16*)(lds + 65536 + par * 16384 + p * 8192 + w * 1024));
  };

  const int arbase = (w >> 2) * 64 + lrow;
  const int brbase = (w & 3) * 32 + lrow;

  bf16x8 aA[4][2];
  bf16x8 bB[2][2];

  auto readA = [&](int par, int ah) {
#pragma unroll
    for (int i = 0; i < 4; i++)
#pragma unroll
      for (int kk = 0; kk < 2; kk++)
        aA[i][kk] = *reinterpret_cast<const bf16x8*>(
            lds + par * 32768 + (arbase + i * 16 + ah * 128) * 128 +
            ((kk * 64 + lg * 16) ^ sw));
  };
  auto readB = [&](int par) {
#pragma unroll
    for (int j = 0; j < 2; j++)
#pragma unroll
      for (int kk = 0; kk < 2; kk++)
        bB[j][kk] = *reinterpret_cast<const bf16x8*>(
            lds + 65536 + par * 16384 + (brbase + j * 16) * 128 +
            ((kk * 64 + lg * 16) ^ sw));
  };

  f32x4 acc[8][2];
#pragma unroll
  for (int i = 0; i < 8; i++)
#pragma unroll
    for (int j = 0; j < 2; j++) {
      acc[i][j][0] = 0.f; acc[i][j][1] = 0.f; acc[i][j][2] = 0.f; acc[i][j][3] = 0.f;
    }

  const int NT = K >> 6;

  // prologue: A(0) h0,h1; B(0); Ah0(1). 8 loads; drain tile0 (6) -> vmcnt(2)
  stageA(0, 0, 0); stageA(0, 1, 0); stageB(0, 0);
  stageA(1, 0, 1);
  __builtin_amdgcn_sched_barrier(0);
  asm volatile("s_waitcnt vmcnt(2)" ::: "memory");
  SBAR();

  for (int t = 0; t < NT; t++) {
    const int par = t & 1, npar = par ^ 1;
    const int t1 = (t + 1 < NT) ? t + 1 : 0;
    const int t2 = (t + 2 < NT) ? t + 2 : 0;

#define MFMA_HALF(AH)                                                        \
  __builtin_amdgcn_s_setprio(1);                                             \
  _Pragma("unroll") for (int i4 = 0; i4 < 4; i4++)                           \
      _Pragma("unroll") for (int j2 = 0; j2 < 2; j2++)                       \
          _Pragma("unroll") for (int kk = 0; kk < 2; kk++)                   \
              acc[(AH)*4 + i4][j2] =                                         \
                  mfma16(aA[i4][kk], bB[j2][kk], acc[(AH)*4 + i4][j2]);      \
  __builtin_amdgcn_s_setprio(0);

    // ph0
    readA(par, 0);
    readB(par);
    stageA(npar, 1, t1);
    stageB(npar, t1);
    SBAR();
    MFMA_HALF(0);
    SBAR();
    // ph1
    readA(par, 1);
    stageA(par, 0, t2);
    SBAR();
    MFMA_HALF(1);
    __builtin_amdgcn_sched_barrier(0);
    asm volatile("s_waitcnt vmcnt(2)" ::: "memory");
    SBAR();
#undef MFMA_HALF
  }

#pragma unroll
  for (int i = 0; i < 8; i++) {
    int row = m0 + (w >> 2) * 64 + (i & 3) * 16 + (i >> 2) * 128 + lg * 4;
#pragma unroll
    for (int j = 0; j < 2; j++) {
      int col = n0 + (w & 3) * 32 + j * 16 + lrow;
#pragma unroll
      for (int jj = 0; jj < 4; jj++)
        C[(size_t)(row + jj) * N + col] = (CT)acc[i][j][jj];
    }
  }
}

// ---------------------------------------------------------------------------
// RoPE, in-place on fused qkv buffer, vectorized. One 256-thread block per
// row. Thread t: q-head t>>3, pair-chunk (t&7)*8..+8 (bf16x8 at [c] and
// [c+64]); threads<64 additionally do k (8 heads x 8 chunks).
// ---------------------------------------------------------------------------
__global__ __launch_bounds__(256) void rope_kernel(__bf16* __restrict__ qkv,
                                                   const int* __restrict__ pos) {
  int row = blockIdx.x;
  int t = threadIdx.x;
  float p = (float)pos[row];
  __bf16* rbase = qkv + (size_t)row * QKVW;

  {
    int head = t >> 3, chunk = t & 7;
    __bf16* base = rbase + head * HD + chunk * 8;
    bf16x8 x1 = *reinterpret_cast<const bf16x8*>(base);
    bf16x8 x2 = *reinterpret_cast<const bf16x8*>(base + 64);
    bf16x8 o1, o2;
#pragma unroll
    for (int e = 0; e < 8; e++) {
      float ang = p * exp2f(-0.20762050f * (float)(chunk * 8 + e));
      float s, c;
      __sincosf(ang, &s, &c);
      float a = (float)x1[e], b2 = (float)x2[e];
      o1[e] = (__bf16)(a * c - b2 * s);
      o2[e] = (__bf16)(b2 * c + a * s);
    }
    *reinterpret_cast<bf16x8*>(base) = o1;
    *reinterpret_cast<bf16x8*>(base + 64) = o2;
  }
  if (t < 64) {
    int head = t >> 3, chunk = t & 7;
    __bf16* base = rbase + 4096 + head * HD + chunk * 8;
    bf16x8 x1 = *reinterpret_cast<const bf16x8*>(base);
    bf16x8 x2 = *reinterpret_cast<const bf16x8*>(base + 64);
    bf16x8 o1, o2;
#pragma unroll
    for (int e = 0; e < 8; e++) {
      float ang = p * exp2f(-0.20762050f * (float)(chunk * 8 + e));
      float s, c;
      __sincosf(ang, &s, &c);
      float a = (float)x1[e], b2 = (float)x2[e];
      o1[e] = (__bf16)(a * c - b2 * s);
      o2[e] = (__bf16)(b2 * c + a * s);
    }
    *reinterpret_cast<bf16x8*>(base) = o1;
    *reinterpret_cast<bf16x8*>(base + 64) = o2;
  }
}

// ---------------------------------------------------------------------------
// Flash attention, causal, GQA. 8-wave blocks, wave w owns 32 q rows of a
// 256-row q block; KVBLK=64; K/V^T reg-staged to XOR-swizzled LDS; T14 split.
// Reads fused qkv buffer (q at col 0, k at col 4096), V^T from vt.
// ---------------------------------------------------------------------------
__global__ __launch_bounds__(512) void attn_kernel(const __bf16* __restrict__ qkv,
                                                   const __bf16* __restrict__ vt,
                                                   __bf16* __restrict__ out) {
  __shared__ __bf16 Ks[64 * 128];      // [kv][d], swizzled, 16 KB
  __shared__ __bf16 Vs[128 * 64];      // [d][kv], swizzled, 16 KB
  __shared__ __bf16 Ps[8][32][68];     // per-wave P, padded, 34 KB

  int tid = threadIdx.x;
  int l = tid & 63, w = tid >> 6;
  int bid = blockIdx.x;
  int qblk = 7 - (bid >> 6);           // heavy blocks first
  int rem = bid & 63;
  int h = rem & 31, b = rem >> 5;
  int kvh = h >> 2;
  int q0w = qblk * 256 + w * 32;
  int lrow = l & 15, lg = l >> 4;
  int sw = (lrow & 7) << 4;
  const float SCL = 0.08838834764831845f * 1.4426950408889634f;  // 1/sqrt(128)*log2e

  const __bf16* kbase = qkv + (size_t)(b * S_LEN) * QKVW + 4096 + kvh * HD;
  const __bf16* vbase = vt + ((size_t)(b * NKV + kvh) * HD) * S_LEN;

  int krow = tid >> 3;                 // 0..63
  int kslot = (tid & 7) * 2;           // 0..14
  int vrow = tid >> 2;                 // 0..127
  int vslot = (tid & 3) * 2;           // 0..6
  char* KsB = (char*)Ks;
  char* VsB = (char*)Vs;
  int koff0 = krow * 256 + ((kslot * 16) ^ ((krow & 7) << 4));
  int koff1 = krow * 256 + (((kslot + 1) * 16) ^ ((krow & 7) << 4));
  int voff0 = vrow * 128 + ((vslot * 16) ^ ((vrow & 7) << 4));
  int voff1 = vrow * 128 + (((vslot + 1) * 16) ^ ((vrow & 7) << 4));
  const __bf16* kg = kbase + (size_t)krow * QKVW + kslot * 8;
  const __bf16* vg = vbase + (size_t)vrow * S_LEN + vslot * 8;

  // Q fragments, pre-scaled
  bf16x8 qf[2][4];
#pragma unroll
  for (int mi = 0; mi < 2; mi++) {
    const __bf16* qp = qkv + (size_t)(b * S_LEN + q0w + mi * 16 + lrow) * QKVW + h * HD + lg * 8;
#pragma unroll
    for (int kk = 0; kk < 4; kk++) {
      bf16x8 t = *reinterpret_cast<const bf16x8*>(qp + kk * 32);
#pragma unroll
      for (int e = 0; e < 8; e++) t[e] = (__bf16)((float)t[e] * SCL);
      qf[mi][kk] = t;
    }
  }

  f32x4 ov[2][8];
#pragma unroll
  for (int mi = 0; mi < 2; mi++)
#pragma unroll
    for (int n = 0; n < 8; n++) {
      ov[mi][n][0] = 0.f; ov[mi][n][1] = 0.f; ov[mi][n][2] = 0.f; ov[mi][n][3] = 0.f;
    }
  float m[2][4], ssum[2][4];
#pragma unroll
  for (int mi = 0; mi < 2; mi++)
#pragma unroll
    for (int jj = 0; jj < 4; jj++) { m[mi][jj] = -3.0e38f; ssum[mi][jj] = 0.f; }

  int nt = 4 * qblk + 4;
  bf16x8 kr0, kr1, vr0, vr1;

  kr0 = *reinterpret_cast<const bf16x8*>(kg);
  kr1 = *reinterpret_cast<const bf16x8*>(kg + 8);
  vr0 = *reinterpret_cast<const bf16x8*>(vg);
  vr1 = *reinterpret_cast<const bf16x8*>(vg + 8);
  *reinterpret_cast<bf16x8*>(KsB + koff0) = kr0;
  *reinterpret_cast<bf16x8*>(KsB + koff1) = kr1;
  *reinterpret_cast<bf16x8*>(VsB + voff0) = vr0;
  *reinterpret_cast<bf16x8*>(VsB + voff1) = vr1;
  __syncthreads();

  for (int t = 0;; t++) {
    int kv0 = t * 64;
    bool more = (t + 1 < nt);
    if (more) {
      int kvn = kv0 + 64;
      kr0 = *reinterpret_cast<const bf16x8*>(kg + (size_t)kvn * QKVW);
      kr1 = *reinterpret_cast<const bf16x8*>(kg + (size_t)kvn * QKVW + 8);
      vr0 = *reinterpret_cast<const bf16x8*>(vg + kvn);
      vr1 = *reinterpret_cast<const bf16x8*>(vg + kvn + 8);
    }

    bool active = (kv0 <= q0w + 31);
    if (active) {
      f32x4 sc[2][4];
#pragma unroll
      for (int mi = 0; mi < 2; mi++)
#pragma unroll
        for (int c = 0; c < 4; c++) {
          sc[mi][c][0] = 0.f; sc[mi][c][1] = 0.f; sc[mi][c][2] = 0.f; sc[mi][c][3] = 0.f;
        }
#pragma unroll
      for (int c = 0; c < 4; c++) {
        int rb = (c * 16 + lrow) * 256;
#pragma unroll
        for (int kk = 0; kk < 4; kk++) {
          bf16x8 kf = *reinterpret_cast<const bf16x8*>(KsB + rb + ((kk * 64 + lg * 16) ^ sw));
          sc[0][c] = mfma16(qf[0][kk], kf, sc[0][c]);
          sc[1][c] = mfma16(qf[1][kk], kf, sc[1][c]);
        }
      }

      bool bound = (kv0 + 64 > q0w);
      float es[2][4];
      bool anyr = false;
#pragma unroll
      for (int mi = 0; mi < 2; mi++)
#pragma unroll
        for (int jj = 0; jj < 4; jj++) {
          int qidx = q0w + mi * 16 + lg * 4 + jj;
          float s0 = sc[mi][0][jj], s1 = sc[mi][1][jj];
          float s2 = sc[mi][2][jj], s3 = sc[mi][3][jj];
          if (bound) {
            if (kv0 + lrow > qidx)      s0 = -3.0e38f;
            if (kv0 + 16 + lrow > qidx) s1 = -3.0e38f;
            if (kv0 + 32 + lrow > qidx) s2 = -3.0e38f;
            if (kv0 + 48 + lrow > qidx) s3 = -3.0e38f;
          }
          float r = fmaxf(fmaxf(s0, s1), fmaxf(s2, s3));
          r = fmaxf(r, __shfl_xor(r, 1));
          r = fmaxf(r, __shfl_xor(r, 2));
          r = fmaxf(r, __shfl_xor(r, 4));
          r = fmaxf(r, __shfl_xor(r, 8));
          float mo = m[mi][jj];
          float mn = fmaxf(mo, r);
          float e = exp2f(mo - mn);
          es[mi][jj] = e;
          anyr |= (mn > mo);
          m[mi][jj] = mn;
          float p0 = exp2f(s0 - mn), p1 = exp2f(s1 - mn);
          float p2 = exp2f(s2 - mn), p3 = exp2f(s3 - mn);
          ssum[mi][jj] = ssum[mi][jj] * e + ((p0 + p1) + (p2 + p3));
          int pr = mi * 16 + lg * 4 + jj;
          Ps[w][pr][lrow]      = (__bf16)p0;
          Ps[w][pr][16 + lrow] = (__bf16)p1;
          Ps[w][pr][32 + lrow] = (__bf16)p2;
          Ps[w][pr][48 + lrow] = (__bf16)p3;
        }
      if (__any(anyr)) {
#pragma unroll
        for (int mi = 0; mi < 2; mi++)
#pragma unroll
          for (int n = 0; n < 8; n++)
#pragma unroll
            for (int jj = 0; jj < 4; jj++) ov[mi][n][jj] *= es[mi][jj];
      }

#pragma unroll
      for (int kvs = 0; kvs < 2; kvs++) {
        bf16x8 pf0 = *reinterpret_cast<const bf16x8*>(&Ps[w][lrow][kvs * 32 + lg * 8]);
        bf16x8 pf1 = *reinterpret_cast<const bf16x8*>(&Ps[w][16 + lrow][kvs * 32 + lg * 8]);
#pragma unroll
        for (int n = 0; n < 8; n++) {
          bf16x8 vf = *reinterpret_cast<const bf16x8*>(
              VsB + (n * 16 + lrow) * 128 + ((kvs * 64 + lg * 16) ^ sw));
          ov[0][n] = mfma16(pf0, vf, ov[0][n]);
          ov[1][n] = mfma16(pf1, vf, ov[1][n]);
        }
      }
    }

    if (!more) break;
    __syncthreads();
    *reinterpret_cast<bf16x8*>(KsB + koff0) = kr0;
    *reinterpret_cast<bf16x8*>(KsB + koff1) = kr1;
    *reinterpret_cast<bf16x8*>(VsB + voff0) = vr0;
    *reinterpret_cast<bf16x8*>(VsB + voff1) = vr1;
    __syncthreads();
  }

  float rinv[2][4];
#pragma unroll
  for (int mi = 0; mi < 2; mi++)
#pragma unroll
    for (int jj = 0; jj < 4; jj++) {
      float s = ssum[mi][jj];
      s += __shfl_xor(s, 1);
      s += __shfl_xor(s, 2);
      s += __shfl_xor(s, 4);
      s += __shfl_xor(s, 8);
      rinv[mi][jj] = 1.0f / s;
    }
#pragma unroll
  for (int mi = 0; mi < 2; mi++)
#pragma unroll
    for (int n = 0; n < 8; n++)
#pragma unroll
      for (int jj = 0; jj < 4; jj++) {
        out[(size_t)(b * S_LEN + q0w + mi * 16 + lg * 4 + jj) * HIDDEN + h * HD + n * 16 + lrow] =
            (__bf16)(ov[mi][n][jj] * rinv[mi][jj]);
      }
}

// ---------------------------------------------------------------------------
// Workspace layout (bytes), total 142606336:
//   h_bf / a_buf (aliased) @ 0          33554432   bf16 [4096][4096]
//   Wt (qkv^T, later Wo^T) @ 33554432   50331648   bf16 [6144][4096]
//   qkv_buf                @ 83886080   50331648   bf16 [4096][6144]
//   vt_buf                 @ 134217728   8388608   bf16 [16][128][2048]
// ---------------------------------------------------------------------------
extern "C" void kernel_launch(void* const* d_in, const int* in_sizes, int n_in,
                              void* d_out, int out_size, void* d_ws, size_t ws_size,
                              hipStream_t stream) {
  const float* hidden = (const float*)d_in[0];
  const int* posids   = (const int*)d_in[1];
  const float* Wq     = (const float*)d_in[2];
  const float* Wk     = (const float*)d_in[3];
  const float* Wv     = (const float*)d_in[4];
  const float* Wo     = (const float*)d_in[5];
  float* out = (float*)d_out;

  char* ws = (char*)d_ws;
  __bf16* h_bf    = (__bf16*)(ws + 0);
  __bf16* a_buf   = h_bf;  // aliased: h last read by QKV GEMM, before attn writes
  __bf16* Wt      = (__bf16*)(ws + 33554432);
  __bf16* qkv_buf = (__bf16*)(ws + 83886080);
  __bf16* vt_buf  = (__bf16*)(ws + 134217728);

  dim3 b256(256), b328(32, 8), b512(512);

  // 1. hidden -> bf16
  cvt_kernel<<<dim3(MROWS * HIDDEN / (256 * 8)), b256, 0, stream>>>(hidden, h_bf, MROWS * HIDDEN);

  // 2. fused weight transpose: Wt = [Wq^T ; Wk^T ; Wv^T]  [6144][4096]
  tcvt_f32<<<dim3(HIDDEN / 32, HIDDEN / 32), b328, 0, stream>>>(Wq, Wt, HIDDEN, HIDDEN);
  tcvt_f32<<<dim3((NKV * HD) / 32, HIDDEN / 32), b328, 0, stream>>>(
      Wk, Wt + (size_t)4096 * 4096, HIDDEN, NKV * HD);
  tcvt_f32<<<dim3((NKV * HD) / 32, HIDDEN / 32), b328, 0, stream>>>(
      Wv, Wt + (size_t)5120 * 4096, HIDDEN, NKV * HD);

  // 3. fused QKV GEMM: qkv = h @ [Wq|Wk|Wv]  (M=4096, N=6144, K=4096)
  //    256x128 tiles -> 16*48 = 768 blocks = 3 balanced rounds.
  gemm128<__bf16><<<dim3((QKVW / 128) * (MROWS / 256)), b512, 0, stream>>>(
      h_bf, Wt, qkv_buf, MROWS, QKVW, HIDDEN, QKVW / 128);

  // 4. RoPE on q,k (in fused buffer), vectorized
  rope_kernel<<<dim3(MROWS), b256, 0, stream>>>(qkv_buf, posids);

  // 5. V^T
  tvt_kernel<<<dim3(HD / 32, S_LEN / 32, BATCH * NKV), b328, 0, stream>>>(qkv_buf, vt_buf);

  // 6. attention -> a_buf
  attn_kernel<<<dim3(8 * NH * BATCH), b512, 0, stream>>>(qkv_buf, vt_buf, a_buf);

  // 7. Wo^T (reuse Wt)
  tcvt_f32<<<dim3(HIDDEN / 32, HIDDEN / 32), b328, 0, stream>>>(Wo, Wt, HIDDEN, HIDDEN);

  // 8. out = a @ Wo  (fp32 out; 256 blocks = 1 balanced round)
  gemm256<float><<<dim3((HIDDEN / 256) * (MROWS / 256)), b512, 0, stream>>>(
      a_buf, Wt, out, MROWS, HIDDEN, HIDDEN, HIDDEN / 256);
}